// Round 1
// baseline (466.039 us; speedup 1.0000x reference)
//
#include <hip/hip_runtime.h>
#include <math.h>

#define B_  32
#define D_  256
#define L_  4096
#define S_  64
#define C3_ 192

#define YSZ    ((size_t)B_ * D_ * L_)   /* 33554432 */
#define HOUTSZ ((size_t)B_ * D_ * S_)   /* 524288  */

// ---------------------------------------------------------------------------
// K1: bcdt_pre[b][o][l] = b_bcdt[o] + sum_k w_bcdt[o][k] * x[b][k][l]
// tile 64o x 64l, K-step 16, 256 threads, 4x4 micro
// ---------------------------------------------------------------------------
__global__ __launch_bounds__(256) void k1_bcdt(
    const float* __restrict__ x, const float* __restrict__ w,
    const float* __restrict__ bias, float* __restrict__ out)
{
    __shared__ float At[16][68];  // [k][o], padded to 68 (16B-aligned rows)
    __shared__ float Bt[16][64];  // [k][l]
    const int b  = blockIdx.z;
    const int o0 = blockIdx.y * 64;
    const int l0 = blockIdx.x * 64;
    const int tid = threadIdx.x;
    const int tx = tid & 15, ty = tid >> 4;
    float acc[4][4] = {};
    const float* xb = x + (size_t)b * D_ * L_;
    for (int k0 = 0; k0 < D_; k0 += 16) {
        {   // A: 64o x 16k  (o fastest over lanes; W is tiny & L2-hot)
            int o = tid & 15, k = tid >> 4;
            #pragma unroll
            for (int i = 0; i < 4; ++i)
                At[k][o + 16 * i] = w[(size_t)(o0 + o + 16 * i) * D_ + k0 + k];
        }
        {   // B: 16k x 64l, coalesced along l
            int l = tid & 63, k = tid >> 6;
            #pragma unroll
            for (int i = 0; i < 4; ++i)
                Bt[k + 4 * i][l] = xb[(size_t)(k0 + k + 4 * i) * L_ + l0 + l];
        }
        __syncthreads();
        #pragma unroll
        for (int k = 0; k < 16; ++k) {
            float a[4], bb[4];
            #pragma unroll
            for (int i = 0; i < 4; ++i) a[i] = At[k][ty * 4 + i];
            #pragma unroll
            for (int j = 0; j < 4; ++j) bb[j] = Bt[k][tx * 4 + j];
            #pragma unroll
            for (int i = 0; i < 4; ++i)
                #pragma unroll
                for (int j = 0; j < 4; ++j)
                    acc[i][j] += a[i] * bb[j];
        }
        __syncthreads();
    }
    float* ob = out + (size_t)b * C3_ * L_;
    #pragma unroll
    for (int i = 0; i < 4; ++i) {
        int o = o0 + ty * 4 + i;
        float bv = bias[o];
        #pragma unroll
        for (int j = 0; j < 4; ++j)
            ob[(size_t)o * L_ + l0 + tx * 4 + j] = acc[i][j] + bv;
    }
}

// ---------------------------------------------------------------------------
// K2a: depthwise 3x3 conv (pad 1) for Cm channels (64..127) -> cm[b][s][l]
// one block per (b,s) plane of 64x64
// ---------------------------------------------------------------------------
__global__ __launch_bounds__(256) void k2a_conv_cm(
    const float* __restrict__ pre, const float* __restrict__ wdw,
    const float* __restrict__ bdw, float* __restrict__ cm)
{
    __shared__ float sm[66][66];
    const int s = blockIdx.x;
    const int b = blockIdx.y;
    const int c = 64 + s;
    const int tid = threadIdx.x;
    for (int i = tid; i < 66 * 66; i += 256) (&sm[0][0])[i] = 0.f;
    __syncthreads();
    const float* ip = pre + ((size_t)b * C3_ + c) * L_;
    for (int p = tid; p < 4096; p += 256)
        sm[(p >> 6) + 1][(p & 63) + 1] = ip[p];
    __syncthreads();
    const float* wp = wdw + c * 9;
    float w00 = wp[0], w01 = wp[1], w02 = wp[2],
          w10 = wp[3], w11 = wp[4], w12 = wp[5],
          w20 = wp[6], w21 = wp[7], w22 = wp[8];
    float bb = bdw[c];
    float* op = cm + ((size_t)b * S_ + s) * L_;
    for (int p = tid; p < 4096; p += 256) {
        int yy = p >> 6, xx = p & 63;
        op[p] = bb
            + sm[yy][xx] * w00     + sm[yy][xx + 1] * w01     + sm[yy][xx + 2] * w02
            + sm[yy + 1][xx] * w10 + sm[yy + 1][xx + 1] * w11 + sm[yy + 1][xx + 2] * w12
            + sm[yy + 2][xx] * w20 + sm[yy + 2][xx + 1] * w21 + sm[yy + 2][xx + 2] * w22;
    }
}

// ---------------------------------------------------------------------------
// K2b: conv(dt ch 128+s) -> softmax over L -> * conv(Bm ch s) -> ab[b][s][l]
// (A_param cancels inside softmax: constant along L)
// ---------------------------------------------------------------------------
__global__ __launch_bounds__(256) void k2b_softmax_ab(
    const float* __restrict__ pre, const float* __restrict__ wdw,
    const float* __restrict__ bdw, float* __restrict__ ab)
{
    __shared__ float sm[66][66];
    __shared__ float red[4];
    const int s = blockIdx.x;
    const int b = blockIdx.y;
    const int tid = threadIdx.x;
    for (int i = tid; i < 66 * 66; i += 256) (&sm[0][0])[i] = 0.f;
    __syncthreads();
    // ---- dt channel ----
    const int cd = 128 + s;
    {
        const float* ip = pre + ((size_t)b * C3_ + cd) * L_;
        for (int p = tid; p < 4096; p += 256)
            sm[(p >> 6) + 1][(p & 63) + 1] = ip[p];
    }
    __syncthreads();
    float dt[16];
    {
        const float* wp = wdw + cd * 9;
        float w00 = wp[0], w01 = wp[1], w02 = wp[2],
              w10 = wp[3], w11 = wp[4], w12 = wp[5],
              w20 = wp[6], w21 = wp[7], w22 = wp[8];
        float bb = bdw[cd];
        #pragma unroll
        for (int i = 0; i < 16; ++i) {
            int p = tid + 256 * i;
            int yy = p >> 6, xx = p & 63;
            dt[i] = bb
                + sm[yy][xx] * w00     + sm[yy][xx + 1] * w01     + sm[yy][xx + 2] * w02
                + sm[yy + 1][xx] * w10 + sm[yy + 1][xx + 1] * w11 + sm[yy + 1][xx + 2] * w12
                + sm[yy + 2][xx] * w20 + sm[yy + 2][xx + 1] * w21 + sm[yy + 2][xx + 2] * w22;
        }
    }
    // ---- softmax over 4096 values held across the block ----
    float mx = dt[0];
    #pragma unroll
    for (int i = 1; i < 16; ++i) mx = fmaxf(mx, dt[i]);
    #pragma unroll
    for (int off = 32; off >= 1; off >>= 1) mx = fmaxf(mx, __shfl_xor(mx, off, 64));
    if ((tid & 63) == 0) red[tid >> 6] = mx;
    __syncthreads();
    mx = fmaxf(fmaxf(red[0], red[1]), fmaxf(red[2], red[3]));
    float e[16];
    float lsum = 0.f;
    #pragma unroll
    for (int i = 0; i < 16; ++i) { e[i] = expf(dt[i] - mx); lsum += e[i]; }
    #pragma unroll
    for (int off = 32; off >= 1; off >>= 1) lsum += __shfl_xor(lsum, off, 64);
    __syncthreads();              // red reuse guard
    if ((tid & 63) == 0) red[tid >> 6] = lsum;
    __syncthreads();
    const float inv = 1.f / (red[0] + red[1] + red[2] + red[3]);
    // ---- Bm channel (reuse sm; borders still zero) ----
    {
        const float* ip = pre + ((size_t)b * C3_ + s) * L_;
        for (int p = tid; p < 4096; p += 256)
            sm[(p >> 6) + 1][(p & 63) + 1] = ip[p];
    }
    __syncthreads();
    {
        const float* wp = wdw + s * 9;
        float w00 = wp[0], w01 = wp[1], w02 = wp[2],
              w10 = wp[3], w11 = wp[4], w12 = wp[5],
              w20 = wp[6], w21 = wp[7], w22 = wp[8];
        float bb = bdw[s];
        float* op = ab + ((size_t)b * S_ + s) * L_;
        #pragma unroll
        for (int i = 0; i < 16; ++i) {
            int p = tid + 256 * i;
            int yy = p >> 6, xx = p & 63;
            float bm = bb
                + sm[yy][xx] * w00     + sm[yy][xx + 1] * w01     + sm[yy][xx + 2] * w02
                + sm[yy + 1][xx] * w10 + sm[yy + 1][xx + 1] * w11 + sm[yy + 1][xx + 2] * w12
                + sm[yy + 2][xx] * w20 + sm[yy + 2][xx + 1] * w21 + sm[yy + 2][xx + 2] * w22;
            op[p] = e[i] * inv * bm;
        }
    }
}

// ---------------------------------------------------------------------------
// K3: split-K partials  hp[chunk][b][d][s] = sum_{l in chunk} x[b,d,l]*ab[b,s,l]
// tile 64d x 64s, l-chunk 512 staged 64 at a time, 4x4 micro
// ---------------------------------------------------------------------------
__global__ __launch_bounds__(256) void k3_hpart(
    const float* __restrict__ x, const float* __restrict__ ab,
    float* __restrict__ hp)
{
    __shared__ float As[64][65];  // [l][d]
    __shared__ float Bs[64][65];  // [l][s]
    const int d0    = blockIdx.x * 64;
    const int b     = blockIdx.y;
    const int chunk = blockIdx.z;
    const int tid = threadIdx.x;
    const int tx = tid & 15, ty = tid >> 4;
    float acc[4][4] = {};
    const float* xb  = x  + (size_t)b * D_ * L_;
    const float* abb = ab + (size_t)b * S_ * L_;
    for (int lt = 0; lt < 512; lt += 64) {
        const int lb = chunk * 512 + lt;
        {
            int l = tid & 63, r = tid >> 6;
            #pragma unroll
            for (int i = 0; i < 16; ++i) {
                int d = r + 4 * i;
                As[l][d] = xb[(size_t)(d0 + d) * L_ + lb + l];
                Bs[l][d] = abb[(size_t)d * L_ + lb + l];
            }
        }
        __syncthreads();
        #pragma unroll
        for (int k = 0; k < 64; ++k) {
            float a[4], bb[4];
            #pragma unroll
            for (int i = 0; i < 4; ++i) a[i] = As[k][ty * 4 + i];
            #pragma unroll
            for (int j = 0; j < 4; ++j) bb[j] = Bs[k][tx * 4 + j];
            #pragma unroll
            for (int i = 0; i < 4; ++i)
                #pragma unroll
                for (int j = 0; j < 4; ++j)
                    acc[i][j] += a[i] * bb[j];
        }
        __syncthreads();
    }
    #pragma unroll
    for (int i = 0; i < 4; ++i)
        #pragma unroll
        for (int j = 0; j < 4; ++j)
            hp[(((size_t)chunk * B_ + b) * D_ + d0 + ty * 4 + i) * S_ + tx * 4 + j] = acc[i][j];
}

__global__ __launch_bounds__(256) void k3r_reduce(
    const float* __restrict__ hp, float* __restrict__ h)
{
    size_t i = (size_t)blockIdx.x * 256 + threadIdx.x;
    float sum = 0.f;
    #pragma unroll
    for (int c = 0; c < 8; ++c) sum += hp[(size_t)c * HOUTSZ + i];
    h[i] = sum;
}

// ---------------------------------------------------------------------------
// K4a: hz = w_hz @ h + b_hz; g = h2 * (silu(z) + D)
// one block: 64 o-rows of h2 AND matching z rows; K=256 step 16
// ---------------------------------------------------------------------------
__global__ __launch_bounds__(256) void k4a_gate(
    const float* __restrict__ h, const float* __restrict__ whz,
    const float* __restrict__ bhz, const float* __restrict__ Dp,
    float* __restrict__ g)
{
    __shared__ float Ah[16][68];  // [k][o] rows o0..
    __shared__ float Az[16][68];  // [k][o] rows o0+256..
    __shared__ float Bs[16][64];  // [k][s]
    const int o0 = blockIdx.x * 64;
    const int b  = blockIdx.y;
    const int tid = threadIdx.x;
    const int tx = tid & 15, ty = tid >> 4;
    float acch[4][4] = {}, accz[4][4] = {};
    const float* hb = h + (size_t)b * D_ * S_;
    for (int k0 = 0; k0 < D_; k0 += 16) {
        {
            int o = tid & 15, k = tid >> 4;
            #pragma unroll
            for (int i = 0; i < 4; ++i) {
                Ah[k][o + 16 * i] = whz[(size_t)(o0 + o + 16 * i) * D_ + k0 + k];
                Az[k][o + 16 * i] = whz[(size_t)(o0 + o + 16 * i + 256) * D_ + k0 + k];
            }
        }
        {
            int s = tid & 63, k = tid >> 6;
            #pragma unroll
            for (int i = 0; i < 4; ++i)
                Bs[k + 4 * i][s] = hb[(size_t)(k0 + k + 4 * i) * S_ + s];
        }
        __syncthreads();
        #pragma unroll
        for (int k = 0; k < 16; ++k) {
            float ah[4], az[4], bb[4];
            #pragma unroll
            for (int i = 0; i < 4; ++i) { ah[i] = Ah[k][ty * 4 + i]; az[i] = Az[k][ty * 4 + i]; }
            #pragma unroll
            for (int j = 0; j < 4; ++j) bb[j] = Bs[k][tx * 4 + j];
            #pragma unroll
            for (int i = 0; i < 4; ++i)
                #pragma unroll
                for (int j = 0; j < 4; ++j) {
                    acch[i][j] += ah[i] * bb[j];
                    accz[i][j] += az[i] * bb[j];
                }
        }
        __syncthreads();
    }
    const float dp = Dp[0];
    #pragma unroll
    for (int i = 0; i < 4; ++i) {
        int o = o0 + ty * 4 + i;
        float bh = bhz[o], bz = bhz[o + 256];
        #pragma unroll
        for (int j = 0; j < 4; ++j) {
            float h2 = acch[i][j] + bh;
            float z  = accz[i][j] + bz;
            float sil = z / (1.f + expf(-z));
            g[((size_t)b * D_ + o) * S_ + tx * 4 + j] = h2 * (sil + dp);
        }
    }
}

// ---------------------------------------------------------------------------
// K4b: hout = w_out @ g + b_out   -> written straight into d_out (output 1)
// ---------------------------------------------------------------------------
__global__ __launch_bounds__(256) void k4b_hout(
    const float* __restrict__ g, const float* __restrict__ wout,
    const float* __restrict__ bout, float* __restrict__ hout)
{
    __shared__ float At[16][68];
    __shared__ float Bs[16][64];
    const int o0 = blockIdx.x * 64;
    const int b  = blockIdx.y;
    const int tid = threadIdx.x;
    const int tx = tid & 15, ty = tid >> 4;
    float acc[4][4] = {};
    const float* gb = g + (size_t)b * D_ * S_;
    for (int k0 = 0; k0 < D_; k0 += 16) {
        {
            int o = tid & 15, k = tid >> 4;
            #pragma unroll
            for (int i = 0; i < 4; ++i)
                At[k][o + 16 * i] = wout[(size_t)(o0 + o + 16 * i) * D_ + k0 + k];
        }
        {
            int s = tid & 63, k = tid >> 6;
            #pragma unroll
            for (int i = 0; i < 4; ++i)
                Bs[k + 4 * i][s] = gb[(size_t)(k0 + k + 4 * i) * S_ + s];
        }
        __syncthreads();
        #pragma unroll
        for (int k = 0; k < 16; ++k) {
            float a[4], bb[4];
            #pragma unroll
            for (int i = 0; i < 4; ++i) a[i] = At[k][ty * 4 + i];
            #pragma unroll
            for (int j = 0; j < 4; ++j) bb[j] = Bs[k][tx * 4 + j];
            #pragma unroll
            for (int i = 0; i < 4; ++i)
                #pragma unroll
                for (int j = 0; j < 4; ++j)
                    acc[i][j] += a[i] * bb[j];
        }
        __syncthreads();
    }
    #pragma unroll
    for (int i = 0; i < 4; ++i) {
        int o = o0 + ty * 4 + i;
        float bv = bout[o];
        #pragma unroll
        for (int j = 0; j < 4; ++j)
            hout[((size_t)b * D_ + o) * S_ + tx * 4 + j] = acc[i][j] + bv;
    }
}

// ---------------------------------------------------------------------------
// K5: y[b][d][l] = sum_s hout[b][d][s] * cm[b][s][l]
// K=64 fully staged; tile 64d x 128l; micro 4x8
// ---------------------------------------------------------------------------
__global__ __launch_bounds__(256) void k5_expand(
    const float* __restrict__ hout, const float* __restrict__ cm,
    float* __restrict__ y)
{
    __shared__ float HT[64][68];   // [s][d]
    __shared__ float CT[64][128];  // [s][l]
    const int l0 = blockIdx.x * 128;
    const int d0 = blockIdx.y * 64;
    const int b  = blockIdx.z;
    const int tid = threadIdx.x;
    const int tx = tid & 15, ty = tid >> 4;
    {
        int s = tid & 63, r = tid >> 6;
        #pragma unroll
        for (int i = 0; i < 16; ++i) {
            int d = r + 4 * i;
            HT[s][d] = hout[((size_t)b * D_ + d0 + d) * S_ + s];
        }
    }
    {
        int l = tid & 127, r = tid >> 7;
        #pragma unroll
        for (int i = 0; i < 32; ++i) {
            int s = r + 2 * i;
            CT[s][l] = cm[((size_t)b * S_ + s) * L_ + l0 + l];
        }
    }
    __syncthreads();
    float acc[4][8] = {};
    #pragma unroll
    for (int k = 0; k < 64; ++k) {
        float a[4], c[8];
        #pragma unroll
        for (int i = 0; i < 4; ++i) a[i] = HT[k][ty * 4 + i];
        #pragma unroll
        for (int j = 0; j < 8; ++j) c[j] = CT[k][tx * 8 + j];
        #pragma unroll
        for (int i = 0; i < 4; ++i)
            #pragma unroll
            for (int j = 0; j < 8; ++j)
                acc[i][j] += a[i] * c[j];
    }
    #pragma unroll
    for (int i = 0; i < 4; ++i) {
        float* yp = y + ((size_t)b * D_ + d0 + ty * 4 + i) * L_ + l0 + tx * 8;
        #pragma unroll
        for (int j = 0; j < 8; ++j) yp[j] = acc[i][j];
    }
}

// ---------------------------------------------------------------------------
extern "C" void kernel_launch(void* const* d_in, const int* in_sizes, int n_in,
                              void* d_out, int out_size, void* d_ws, size_t ws_size,
                              hipStream_t stream)
{
    const float* x      = (const float*)d_in[0];
    // d_in[1]=H, d_in[2]=W (ints, fixed 64)
    const float* w_bcdt = (const float*)d_in[3];
    const float* b_bcdt = (const float*)d_in[4];
    const float* w_dw   = (const float*)d_in[5];
    const float* b_dw   = (const float*)d_in[6];
    const float* w_hz   = (const float*)d_in[7];
    const float* b_hz   = (const float*)d_in[8];
    const float* w_out  = (const float*)d_in[9];
    const float* b_out  = (const float*)d_in[10];
    // d_in[11] = A_param: constant along softmax axis L -> cancels, unused
    const float* Dp     = (const float*)d_in[12];

    float* ws  = (float*)d_ws;
    float* pre = ws;                         // 32*192*4096 = 25165824 f
    float* ab  = ws + 25165824;              //  8388608 f
    float* cm  = ab + 8388608;               //  8388608 f
    // pre is dead after K2a/K2b: reuse its region
    float* hp  = pre;                        // 8*524288 = 4194304 f
    float* h   = pre + 4194304;              //  524288 f
    float* g   = pre + 4194304 + 524288;     //  524288 f

    float* y    = (float*)d_out;
    float* hout = (float*)d_out + YSZ;

    k1_bcdt      <<<dim3(64, 3, 32), 256, 0, stream>>>(x, w_bcdt, b_bcdt, pre);
    k2a_conv_cm  <<<dim3(64, 32),    256, 0, stream>>>(pre, w_dw, b_dw, cm);
    k2b_softmax_ab<<<dim3(64, 32),   256, 0, stream>>>(pre, w_dw, b_dw, ab);
    k3_hpart     <<<dim3(4, 32, 8),  256, 0, stream>>>(x, ab, hp);
    k3r_reduce   <<<2048,            256, 0, stream>>>(hp, h);
    k4a_gate     <<<dim3(4, 32),     256, 0, stream>>>(h, w_hz, b_hz, Dp, g);
    k4b_hout     <<<dim3(4, 32),     256, 0, stream>>>(g, w_out, b_out, hout);
    k5_expand    <<<dim3(32, 4, 32), 256, 0, stream>>>(hout, cm, y);
}

// Round 2
// 293.686 us; speedup vs baseline: 1.5869x; 1.5869x over previous
//
#include <hip/hip_runtime.h>
#include <math.h>

#define B_  32
#define D_  256
#define L_  4096
#define S_  64
#define C3_ 192

#define YSZ    ((size_t)B_ * D_ * L_)   /* 33554432 */
#define HOUTSZ ((size_t)B_ * D_ * S_)   /* 524288  */

typedef __attribute__((ext_vector_type(8))) short short8;
typedef __attribute__((ext_vector_type(4))) float f32x4;

__device__ __forceinline__ short f2bf(float f) {
    unsigned u = __float_as_uint(f);
    u += 0x7fffu + ((u >> 16) & 1u);   // round-to-nearest-even
    return (short)(u >> 16);
}

// ---------------------------------------------------------------------------
// K1 (MFMA): pre[b][o][l] = b_bcdt[o] + sum_d w[o][d] * x[b][d][l]
// M=192 (all o), N=128 l-tile, K=256 in steps of 32. 4 waves, 12x2 frags each.
// x fragments need d-contiguous: transpose during staging (scalar dword loads,
// lane-coalesced along l) -> B_lds[l][d]. LDS rows 40 shorts = 80 B:
// 16B-aligned for b128, bank stride 20 -> 2-way (free).
// ---------------------------------------------------------------------------
__global__ __launch_bounds__(256) void k1_bcdt_mfma(
    const float* __restrict__ x, const float* __restrict__ w,
    const float* __restrict__ bias, float* __restrict__ out)
{
    __shared__ __align__(16) short A_lds[192][40];  // [o][k]
    __shared__ __align__(16) short B_lds[128][40];  // [l][k]
    const int l0 = blockIdx.x * 128;
    const int b  = blockIdx.y;
    const int tid  = threadIdx.x;
    const int lane = tid & 63;
    const int wv   = tid >> 6;
    const int lm   = lane & 15;   // fragment row (A) / col (B)
    const int kg   = lane >> 4;   // k-group: k = kg*8 + j
    const float* xb = x + (size_t)b * D_ * L_;

    f32x4 acc[12][2];
    #pragma unroll
    for (int mi = 0; mi < 12; ++mi)
        #pragma unroll
        for (int nj = 0; nj < 2; ++nj)
            acc[mi][nj] = (f32x4){0.f, 0.f, 0.f, 0.f};

    for (int k0 = 0; k0 < D_; k0 += 32) {
        if (k0) __syncthreads();
        // ---- stage A: w[0..192)[k0..k0+32) ----
        #pragma unroll
        for (int q = 0; q < 3; ++q) {
            int task = q * 256 + tid;              // 0..767
            int o = task >> 2, kk = (task & 3) * 8;
            const float4* wp = reinterpret_cast<const float4*>(
                w + (size_t)o * D_ + k0 + kk);
            float4 p0 = wp[0], p1 = wp[1];
            short8 s;
            s[0] = f2bf(p0.x); s[1] = f2bf(p0.y); s[2] = f2bf(p0.z); s[3] = f2bf(p0.w);
            s[4] = f2bf(p1.x); s[5] = f2bf(p1.y); s[6] = f2bf(p1.z); s[7] = f2bf(p1.w);
            *(short8*)&A_lds[o][kk] = s;
        }
        // ---- stage B: x[k0..k0+32)[l0..l0+128) transposed -> [l][k] ----
        #pragma unroll
        for (int q = 0; q < 2; ++q) {
            int task = q * 256 + tid;              // 0..511
            int l = task & 127, dg = task >> 7;    // dg in 0..3
            const float* xp = xb + (size_t)(k0 + dg * 8) * L_ + l0 + l;
            short8 s;
            #pragma unroll
            for (int r = 0; r < 8; ++r) s[r] = f2bf(xp[(size_t)r * L_]);
            *(short8*)&B_lds[l][dg * 8] = s;
        }
        __syncthreads();
        // ---- MFMA ----
        short8 bb[2];
        #pragma unroll
        for (int nj = 0; nj < 2; ++nj)
            bb[nj] = *(const short8*)&B_lds[wv * 32 + nj * 16 + lm][kg * 8];
        #pragma unroll
        for (int mi = 0; mi < 12; ++mi) {
            short8 a = *(const short8*)&A_lds[mi * 16 + lm][kg * 8];
            #pragma unroll
            for (int nj = 0; nj < 2; ++nj)
                acc[mi][nj] = __builtin_amdgcn_mfma_f32_16x16x32_bf16(
                    a, bb[nj], acc[mi][nj], 0, 0, 0);
        }
    }
    // ---- epilogue: C/D layout col=lane&15, row=(lane>>4)*4+r ----
    float* ob = out + (size_t)b * C3_ * L_;
    const int col = l0 + wv * 32 + lm;
    #pragma unroll
    for (int mi = 0; mi < 12; ++mi) {
        #pragma unroll
        for (int r = 0; r < 4; ++r) {
            int o = mi * 16 + kg * 4 + r;
            float bv = bias[o];
            #pragma unroll
            for (int nj = 0; nj < 2; ++nj)
                ob[(size_t)o * L_ + col + nj * 16] = acc[mi][nj][r] + bv;
        }
    }
}

// ---------------------------------------------------------------------------
// K2a: depthwise 3x3 conv (pad 1) for Cm channels (64..127) -> cm[b][s][l]
// ---------------------------------------------------------------------------
__global__ __launch_bounds__(256) void k2a_conv_cm(
    const float* __restrict__ pre, const float* __restrict__ wdw,
    const float* __restrict__ bdw, float* __restrict__ cm)
{
    __shared__ float sm[66][66];
    const int s = blockIdx.x;
    const int b = blockIdx.y;
    const int c = 64 + s;
    const int tid = threadIdx.x;
    for (int i = tid; i < 66 * 66; i += 256) (&sm[0][0])[i] = 0.f;
    __syncthreads();
    const float* ip = pre + ((size_t)b * C3_ + c) * L_;
    for (int p = tid; p < 4096; p += 256)
        sm[(p >> 6) + 1][(p & 63) + 1] = ip[p];
    __syncthreads();
    const float* wp = wdw + c * 9;
    float w00 = wp[0], w01 = wp[1], w02 = wp[2],
          w10 = wp[3], w11 = wp[4], w12 = wp[5],
          w20 = wp[6], w21 = wp[7], w22 = wp[8];
    float bb = bdw[c];
    float* op = cm + ((size_t)b * S_ + s) * L_;
    for (int p = tid; p < 4096; p += 256) {
        int yy = p >> 6, xx = p & 63;
        op[p] = bb
            + sm[yy][xx] * w00     + sm[yy][xx + 1] * w01     + sm[yy][xx + 2] * w02
            + sm[yy + 1][xx] * w10 + sm[yy + 1][xx + 1] * w11 + sm[yy + 1][xx + 2] * w12
            + sm[yy + 2][xx] * w20 + sm[yy + 2][xx + 1] * w21 + sm[yy + 2][xx + 2] * w22;
    }
}

// ---------------------------------------------------------------------------
// K2b: conv(dt ch 128+s) -> softmax over L -> * conv(Bm ch s) -> ab[b][s][l]
// (A_param cancels inside softmax: constant along L)
// ---------------------------------------------------------------------------
__global__ __launch_bounds__(256) void k2b_softmax_ab(
    const float* __restrict__ pre, const float* __restrict__ wdw,
    const float* __restrict__ bdw, float* __restrict__ ab)
{
    __shared__ float sm[66][66];
    __shared__ float red[4];
    const int s = blockIdx.x;
    const int b = blockIdx.y;
    const int tid = threadIdx.x;
    for (int i = tid; i < 66 * 66; i += 256) (&sm[0][0])[i] = 0.f;
    __syncthreads();
    const int cd = 128 + s;
    {
        const float* ip = pre + ((size_t)b * C3_ + cd) * L_;
        for (int p = tid; p < 4096; p += 256)
            sm[(p >> 6) + 1][(p & 63) + 1] = ip[p];
    }
    __syncthreads();
    float dt[16];
    {
        const float* wp = wdw + cd * 9;
        float w00 = wp[0], w01 = wp[1], w02 = wp[2],
              w10 = wp[3], w11 = wp[4], w12 = wp[5],
              w20 = wp[6], w21 = wp[7], w22 = wp[8];
        float bb = bdw[cd];
        #pragma unroll
        for (int i = 0; i < 16; ++i) {
            int p = tid + 256 * i;
            int yy = p >> 6, xx = p & 63;
            dt[i] = bb
                + sm[yy][xx] * w00     + sm[yy][xx + 1] * w01     + sm[yy][xx + 2] * w02
                + sm[yy + 1][xx] * w10 + sm[yy + 1][xx + 1] * w11 + sm[yy + 1][xx + 2] * w12
                + sm[yy + 2][xx] * w20 + sm[yy + 2][xx + 1] * w21 + sm[yy + 2][xx + 2] * w22;
        }
    }
    float mx = dt[0];
    #pragma unroll
    for (int i = 1; i < 16; ++i) mx = fmaxf(mx, dt[i]);
    #pragma unroll
    for (int off = 32; off >= 1; off >>= 1) mx = fmaxf(mx, __shfl_xor(mx, off, 64));
    if ((tid & 63) == 0) red[tid >> 6] = mx;
    __syncthreads();
    mx = fmaxf(fmaxf(red[0], red[1]), fmaxf(red[2], red[3]));
    float e[16];
    float lsum = 0.f;
    #pragma unroll
    for (int i = 0; i < 16; ++i) { e[i] = expf(dt[i] - mx); lsum += e[i]; }
    #pragma unroll
    for (int off = 32; off >= 1; off >>= 1) lsum += __shfl_xor(lsum, off, 64);
    __syncthreads();
    if ((tid & 63) == 0) red[tid >> 6] = lsum;
    __syncthreads();
    const float inv = 1.f / (red[0] + red[1] + red[2] + red[3]);
    {
        const float* ip = pre + ((size_t)b * C3_ + s) * L_;
        for (int p = tid; p < 4096; p += 256)
            sm[(p >> 6) + 1][(p & 63) + 1] = ip[p];
    }
    __syncthreads();
    {
        const float* wp = wdw + s * 9;
        float w00 = wp[0], w01 = wp[1], w02 = wp[2],
              w10 = wp[3], w11 = wp[4], w12 = wp[5],
              w20 = wp[6], w21 = wp[7], w22 = wp[8];
        float bb = bdw[s];
        float* op = ab + ((size_t)b * S_ + s) * L_;
        #pragma unroll
        for (int i = 0; i < 16; ++i) {
            int p = tid + 256 * i;
            int yy = p >> 6, xx = p & 63;
            float bm = bb
                + sm[yy][xx] * w00     + sm[yy][xx + 1] * w01     + sm[yy][xx + 2] * w02
                + sm[yy + 1][xx] * w10 + sm[yy + 1][xx + 1] * w11 + sm[yy + 1][xx + 2] * w12
                + sm[yy + 2][xx] * w20 + sm[yy + 2][xx + 1] * w21 + sm[yy + 2][xx + 2] * w22;
            op[p] = e[i] * inv * bm;
        }
    }
}

// ---------------------------------------------------------------------------
// K3: split-K partials  hp[chunk][b][d][s] = sum_{l in chunk} x[b,d,l]*ab[b,s,l]
// (f32 this round; MFMA conversion next round once fragment layout is proven)
// ---------------------------------------------------------------------------
__global__ __launch_bounds__(256) void k3_hpart(
    const float* __restrict__ x, const float* __restrict__ ab,
    float* __restrict__ hp)
{
    __shared__ float As[64][65];
    __shared__ float Bs[64][65];
    const int d0    = blockIdx.x * 64;
    const int b     = blockIdx.y;
    const int chunk = blockIdx.z;
    const int tid = threadIdx.x;
    const int tx = tid & 15, ty = tid >> 4;
    float acc[4][4] = {};
    const float* xb  = x  + (size_t)b * D_ * L_;
    const float* abb = ab + (size_t)b * S_ * L_;
    for (int lt = 0; lt < 512; lt += 64) {
        const int lb = chunk * 512 + lt;
        {
            int l = tid & 63, r = tid >> 6;
            #pragma unroll
            for (int i = 0; i < 16; ++i) {
                int d = r + 4 * i;
                As[l][d] = xb[(size_t)(d0 + d) * L_ + lb + l];
                Bs[l][d] = abb[(size_t)d * L_ + lb + l];
            }
        }
        __syncthreads();
        #pragma unroll
        for (int k = 0; k < 64; ++k) {
            float a[4], bb[4];
            #pragma unroll
            for (int i = 0; i < 4; ++i) a[i] = As[k][ty * 4 + i];
            #pragma unroll
            for (int j = 0; j < 4; ++j) bb[j] = Bs[k][tx * 4 + j];
            #pragma unroll
            for (int i = 0; i < 4; ++i)
                #pragma unroll
                for (int j = 0; j < 4; ++j)
                    acc[i][j] += a[i] * bb[j];
        }
        __syncthreads();
    }
    #pragma unroll
    for (int i = 0; i < 4; ++i)
        #pragma unroll
        for (int j = 0; j < 4; ++j)
            hp[(((size_t)chunk * B_ + b) * D_ + d0 + ty * 4 + i) * S_ + tx * 4 + j] = acc[i][j];
}

__global__ __launch_bounds__(256) void k3r_reduce(
    const float* __restrict__ hp, float* __restrict__ h)
{
    size_t i = (size_t)blockIdx.x * 256 + threadIdx.x;
    float sum = 0.f;
    #pragma unroll
    for (int c = 0; c < 8; ++c) sum += hp[(size_t)c * HOUTSZ + i];
    h[i] = sum;
}

// ---------------------------------------------------------------------------
// K4a: hz = w_hz @ h + b_hz; g = h2 * (silu(z) + D)
// ---------------------------------------------------------------------------
__global__ __launch_bounds__(256) void k4a_gate(
    const float* __restrict__ h, const float* __restrict__ whz,
    const float* __restrict__ bhz, const float* __restrict__ Dp,
    float* __restrict__ g)
{
    __shared__ float Ah[16][68];
    __shared__ float Az[16][68];
    __shared__ float Bs[16][64];
    const int o0 = blockIdx.x * 64;
    const int b  = blockIdx.y;
    const int tid = threadIdx.x;
    const int tx = tid & 15, ty = tid >> 4;
    float acch[4][4] = {}, accz[4][4] = {};
    const float* hb = h + (size_t)b * D_ * S_;
    for (int k0 = 0; k0 < D_; k0 += 16) {
        {
            int o = tid & 15, k = tid >> 4;
            #pragma unroll
            for (int i = 0; i < 4; ++i) {
                Ah[k][o + 16 * i] = whz[(size_t)(o0 + o + 16 * i) * D_ + k0 + k];
                Az[k][o + 16 * i] = whz[(size_t)(o0 + o + 16 * i + 256) * D_ + k0 + k];
            }
        }
        {
            int s = tid & 63, k = tid >> 6;
            #pragma unroll
            for (int i = 0; i < 4; ++i)
                Bs[k + 4 * i][s] = hb[(size_t)(k0 + k + 4 * i) * S_ + s];
        }
        __syncthreads();
        #pragma unroll
        for (int k = 0; k < 16; ++k) {
            float ah[4], az[4], bb[4];
            #pragma unroll
            for (int i = 0; i < 4; ++i) { ah[i] = Ah[k][ty * 4 + i]; az[i] = Az[k][ty * 4 + i]; }
            #pragma unroll
            for (int j = 0; j < 4; ++j) bb[j] = Bs[k][tx * 4 + j];
            #pragma unroll
            for (int i = 0; i < 4; ++i)
                #pragma unroll
                for (int j = 0; j < 4; ++j) {
                    acch[i][j] += ah[i] * bb[j];
                    accz[i][j] += az[i] * bb[j];
                }
        }
        __syncthreads();
    }
    const float dp = Dp[0];
    #pragma unroll
    for (int i = 0; i < 4; ++i) {
        int o = o0 + ty * 4 + i;
        float bh = bhz[o], bz = bhz[o + 256];
        #pragma unroll
        for (int j = 0; j < 4; ++j) {
            float h2 = acch[i][j] + bh;
            float z  = accz[i][j] + bz;
            float sil = z / (1.f + expf(-z));
            g[((size_t)b * D_ + o) * S_ + tx * 4 + j] = h2 * (sil + dp);
        }
    }
}

// ---------------------------------------------------------------------------
// K4b: hout = w_out @ g + b_out -> d_out (output 1)
// ---------------------------------------------------------------------------
__global__ __launch_bounds__(256) void k4b_hout(
    const float* __restrict__ g, const float* __restrict__ wout,
    const float* __restrict__ bout, float* __restrict__ hout)
{
    __shared__ float At[16][68];
    __shared__ float Bs[16][64];
    const int o0 = blockIdx.x * 64;
    const int b  = blockIdx.y;
    const int tid = threadIdx.x;
    const int tx = tid & 15, ty = tid >> 4;
    float acc[4][4] = {};
    const float* gb = g + (size_t)b * D_ * S_;
    for (int k0 = 0; k0 < D_; k0 += 16) {
        {
            int o = tid & 15, k = tid >> 4;
            #pragma unroll
            for (int i = 0; i < 4; ++i)
                At[k][o + 16 * i] = wout[(size_t)(o0 + o + 16 * i) * D_ + k0 + k];
        }
        {
            int s = tid & 63, k = tid >> 6;
            #pragma unroll
            for (int i = 0; i < 4; ++i)
                Bs[k + 4 * i][s] = gb[(size_t)(k0 + k + 4 * i) * S_ + s];
        }
        __syncthreads();
        #pragma unroll
        for (int k = 0; k < 16; ++k) {
            float a[4], bb[4];
            #pragma unroll
            for (int i = 0; i < 4; ++i) a[i] = At[k][ty * 4 + i];
            #pragma unroll
            for (int j = 0; j < 4; ++j) bb[j] = Bs[k][tx * 4 + j];
            #pragma unroll
            for (int i = 0; i < 4; ++i)
                #pragma unroll
                for (int j = 0; j < 4; ++j)
                    acc[i][j] += a[i] * bb[j];
        }
        __syncthreads();
    }
    #pragma unroll
    for (int i = 0; i < 4; ++i) {
        int o = o0 + ty * 4 + i;
        float bv = bout[o];
        #pragma unroll
        for (int j = 0; j < 4; ++j)
            hout[((size_t)b * D_ + o) * S_ + tx * 4 + j] = acc[i][j] + bv;
    }
}

// ---------------------------------------------------------------------------
// K5 (MFMA): y[b][d][l] = sum_s hout[b][d][s] * cm[b][s][l]
// K=64 fully staged. A=[d][s] natural; B=cm transposed -> [l][s] during staging.
// Rows padded to 72 shorts (144 B: 16B-aligned, ~2-way banks).
// ---------------------------------------------------------------------------
__global__ __launch_bounds__(256) void k5_expand_mfma(
    const float* __restrict__ hout, const float* __restrict__ cm,
    float* __restrict__ y)
{
    __shared__ __align__(16) short A_lds[64][72];   // [d][s]
    __shared__ __align__(16) short B_lds[128][72];  // [l][s]
    const int l0 = blockIdx.x * 128;
    const int d0 = blockIdx.y * 64;
    const int b  = blockIdx.z;
    const int tid  = threadIdx.x;
    const int lane = tid & 63;
    const int wv   = tid >> 6;
    const int lm   = lane & 15, kg = lane >> 4;

    // stage A: hout[b][d0+d][s], 64x64, fully coalesced
    #pragma unroll
    for (int q = 0; q < 2; ++q) {
        int task = q * 256 + tid;              // 0..511
        int d = task >> 3, sg = (task & 7) * 8;
        const float4* hp = reinterpret_cast<const float4*>(
            hout + ((size_t)b * D_ + d0 + d) * S_ + sg);
        float4 p0 = hp[0], p1 = hp[1];
        short8 s;
        s[0] = f2bf(p0.x); s[1] = f2bf(p0.y); s[2] = f2bf(p0.z); s[3] = f2bf(p0.w);
        s[4] = f2bf(p1.x); s[5] = f2bf(p1.y); s[6] = f2bf(p1.z); s[7] = f2bf(p1.w);
        *(short8*)&A_lds[d][sg] = s;
    }
    // stage B: cm[b][s][l0+l] transposed -> [l][s]
    #pragma unroll
    for (int q = 0; q < 4; ++q) {
        int l = tid & 127;
        int sg = (q * 2 + (tid >> 7)) * 8;
        const float* cp = cm + ((size_t)b * S_ + sg) * L_ + l0 + l;
        short8 s;
        #pragma unroll
        for (int r = 0; r < 8; ++r) s[r] = f2bf(cp[(size_t)r * L_]);
        *(short8*)&B_lds[l][sg] = s;
    }
    __syncthreads();

    f32x4 acc[4][2];
    #pragma unroll
    for (int mi = 0; mi < 4; ++mi)
        #pragma unroll
        for (int nj = 0; nj < 2; ++nj)
            acc[mi][nj] = (f32x4){0.f, 0.f, 0.f, 0.f};
    #pragma unroll
    for (int ks = 0; ks < 2; ++ks) {
        short8 bb[2];
        #pragma unroll
        for (int nj = 0; nj < 2; ++nj)
            bb[nj] = *(const short8*)&B_lds[wv * 32 + nj * 16 + lm][ks * 32 + kg * 8];
        #pragma unroll
        for (int mi = 0; mi < 4; ++mi) {
            short8 a = *(const short8*)&A_lds[mi * 16 + lm][ks * 32 + kg * 8];
            #pragma unroll
            for (int nj = 0; nj < 2; ++nj)
                acc[mi][nj] = __builtin_amdgcn_mfma_f32_16x16x32_bf16(
                    a, bb[nj], acc[mi][nj], 0, 0, 0);
        }
    }
    const int col = l0 + wv * 32 + lm;
    #pragma unroll
    for (int mi = 0; mi < 4; ++mi)
        #pragma unroll
        for (int r = 0; r < 4; ++r)
            #pragma unroll
            for (int nj = 0; nj < 2; ++nj)
                y[((size_t)b * D_ + d0 + mi * 16 + kg * 4 + r) * L_ + col + nj * 16]
                    = acc[mi][nj][r];
}

// ---------------------------------------------------------------------------
extern "C" void kernel_launch(void* const* d_in, const int* in_sizes, int n_in,
                              void* d_out, int out_size, void* d_ws, size_t ws_size,
                              hipStream_t stream)
{
    const float* x      = (const float*)d_in[0];
    const float* w_bcdt = (const float*)d_in[3];
    const float* b_bcdt = (const float*)d_in[4];
    const float* w_dw   = (const float*)d_in[5];
    const float* b_dw   = (const float*)d_in[6];
    const float* w_hz   = (const float*)d_in[7];
    const float* b_hz   = (const float*)d_in[8];
    const float* w_out  = (const float*)d_in[9];
    const float* b_out  = (const float*)d_in[10];
    // d_in[11] = A_param: constant along softmax axis L -> cancels, unused
    const float* Dp     = (const float*)d_in[12];

    float* ws  = (float*)d_ws;
    float* pre = ws;                         // 32*192*4096 f
    float* ab  = ws + 25165824;              //  8388608 f
    float* cm  = ab + 8388608;               //  8388608 f
    float* hp  = pre;                        // reuse pre after convs
    float* h   = pre + 4194304;
    float* g   = pre + 4194304 + 524288;

    float* y    = (float*)d_out;
    float* hout = (float*)d_out + YSZ;

    k1_bcdt_mfma  <<<dim3(32, 32),    256, 0, stream>>>(x, w_bcdt, b_bcdt, pre);
    k2a_conv_cm   <<<dim3(64, 32),    256, 0, stream>>>(pre, w_dw, b_dw, cm);
    k2b_softmax_ab<<<dim3(64, 32),    256, 0, stream>>>(pre, w_dw, b_dw, ab);
    k3_hpart      <<<dim3(4, 32, 8),  256, 0, stream>>>(x, ab, hp);
    k3r_reduce    <<<2048,            256, 0, stream>>>(hp, h);
    k4a_gate      <<<dim3(4, 32),     256, 0, stream>>>(h, w_hz, b_hz, Dp, g);
    k4b_hout      <<<dim3(4, 32),     256, 0, stream>>>(g, w_out, b_out, hout);
    k5_expand_mfma<<<dim3(32, 4, 32), 256, 0, stream>>>(hout, cm, y);
}

// Round 3
// 256.082 us; speedup vs baseline: 1.8199x; 1.1468x over previous
//
#include <hip/hip_runtime.h>
#include <math.h>

#define B_  32
#define D_  256
#define L_  4096
#define S_  64
#define C3_ 192

#define YSZ    ((size_t)B_ * D_ * L_)   /* 33554432 */
#define HOUTSZ ((size_t)B_ * D_ * S_)   /* 524288  */
#define NCHUNK 16

typedef __attribute__((ext_vector_type(8))) short short8;
typedef __attribute__((ext_vector_type(4))) float f32x4;

__device__ __forceinline__ short f2bf(float f) {
    unsigned u = __float_as_uint(f);
    u += 0x7fffu + ((u >> 16) & 1u);   // round-to-nearest-even
    return (short)(u >> 16);
}

__device__ __forceinline__ short8 ld_cvt8(const float* p) {
    const float4* q = reinterpret_cast<const float4*>(p);
    float4 p0 = q[0], p1 = q[1];
    short8 s;
    s[0] = f2bf(p0.x); s[1] = f2bf(p0.y); s[2] = f2bf(p0.z); s[3] = f2bf(p0.w);
    s[4] = f2bf(p1.x); s[5] = f2bf(p1.y); s[6] = f2bf(p1.z); s[7] = f2bf(p1.w);
    return s;
}

// ---------------------------------------------------------------------------
// K1 (MFMA): pre[b][o][l] = b_bcdt[o] + sum_d w[o][d] * x[b][d][l]
// ---------------------------------------------------------------------------
__global__ __launch_bounds__(256) void k1_bcdt_mfma(
    const float* __restrict__ x, const float* __restrict__ w,
    const float* __restrict__ bias, float* __restrict__ out)
{
    __shared__ __align__(16) short A_lds[192][40];  // [o][k]
    __shared__ __align__(16) short B_lds[128][40];  // [l][k]
    const int l0 = blockIdx.x * 128;
    const int b  = blockIdx.y;
    const int tid  = threadIdx.x;
    const int lane = tid & 63;
    const int wv   = tid >> 6;
    const int lm   = lane & 15;
    const int kg   = lane >> 4;
    const float* xb = x + (size_t)b * D_ * L_;

    f32x4 acc[12][2];
    #pragma unroll
    for (int mi = 0; mi < 12; ++mi)
        #pragma unroll
        for (int nj = 0; nj < 2; ++nj)
            acc[mi][nj] = (f32x4){0.f, 0.f, 0.f, 0.f};

    for (int k0 = 0; k0 < D_; k0 += 32) {
        if (k0) __syncthreads();
        #pragma unroll
        for (int q = 0; q < 3; ++q) {
            int task = q * 256 + tid;
            int o = task >> 2, kk = (task & 3) * 8;
            *(short8*)&A_lds[o][kk] = ld_cvt8(w + (size_t)o * D_ + k0 + kk);
        }
        #pragma unroll
        for (int q = 0; q < 2; ++q) {
            int task = q * 256 + tid;
            int l = task & 127, dg = task >> 7;
            const float* xp = xb + (size_t)(k0 + dg * 8) * L_ + l0 + l;
            short8 s;
            #pragma unroll
            for (int r = 0; r < 8; ++r) s[r] = f2bf(xp[(size_t)r * L_]);
            *(short8*)&B_lds[l][dg * 8] = s;
        }
        __syncthreads();
        short8 bb[2];
        #pragma unroll
        for (int nj = 0; nj < 2; ++nj)
            bb[nj] = *(const short8*)&B_lds[wv * 32 + nj * 16 + lm][kg * 8];
        #pragma unroll
        for (int mi = 0; mi < 12; ++mi) {
            short8 a = *(const short8*)&A_lds[mi * 16 + lm][kg * 8];
            #pragma unroll
            for (int nj = 0; nj < 2; ++nj)
                acc[mi][nj] = __builtin_amdgcn_mfma_f32_16x16x32_bf16(
                    a, bb[nj], acc[mi][nj], 0, 0, 0);
        }
    }
    float* ob = out + (size_t)b * C3_ * L_;
    const int col = l0 + wv * 32 + lm;
    #pragma unroll
    for (int mi = 0; mi < 12; ++mi) {
        #pragma unroll
        for (int r = 0; r < 4; ++r) {
            int o = mi * 16 + kg * 4 + r;
            float bv = bias[o];
            #pragma unroll
            for (int nj = 0; nj < 2; ++nj)
                ob[(size_t)o * L_ + col + nj * 16] = acc[mi][nj][r] + bv;
        }
    }
}

// ---------------------------------------------------------------------------
// K2a: depthwise 3x3 conv (pad 1) for Cm channels (64..127) -> cm[b][s][l]
// ---------------------------------------------------------------------------
__global__ __launch_bounds__(256) void k2a_conv_cm(
    const float* __restrict__ pre, const float* __restrict__ wdw,
    const float* __restrict__ bdw, float* __restrict__ cm)
{
    __shared__ float sm[66][66];
    const int s = blockIdx.x;
    const int b = blockIdx.y;
    const int c = 64 + s;
    const int tid = threadIdx.x;
    for (int i = tid; i < 66 * 66; i += 256) (&sm[0][0])[i] = 0.f;
    __syncthreads();
    const float* ip = pre + ((size_t)b * C3_ + c) * L_;
    for (int p = tid; p < 4096; p += 256)
        sm[(p >> 6) + 1][(p & 63) + 1] = ip[p];
    __syncthreads();
    const float* wp = wdw + c * 9;
    float w00 = wp[0], w01 = wp[1], w02 = wp[2],
          w10 = wp[3], w11 = wp[4], w12 = wp[5],
          w20 = wp[6], w21 = wp[7], w22 = wp[8];
    float bb = bdw[c];
    float* op = cm + ((size_t)b * S_ + s) * L_;
    for (int p = tid; p < 4096; p += 256) {
        int yy = p >> 6, xx = p & 63;
        op[p] = bb
            + sm[yy][xx] * w00     + sm[yy][xx + 1] * w01     + sm[yy][xx + 2] * w02
            + sm[yy + 1][xx] * w10 + sm[yy + 1][xx + 1] * w11 + sm[yy + 1][xx + 2] * w12
            + sm[yy + 2][xx] * w20 + sm[yy + 2][xx + 1] * w21 + sm[yy + 2][xx + 2] * w22;
    }
}

// ---------------------------------------------------------------------------
// K2b: conv(dt ch 128+s) -> softmax over L -> * conv(Bm ch s) -> ab[b][s][l]
// ---------------------------------------------------------------------------
__global__ __launch_bounds__(256) void k2b_softmax_ab(
    const float* __restrict__ pre, const float* __restrict__ wdw,
    const float* __restrict__ bdw, float* __restrict__ ab)
{
    __shared__ float sm[66][66];
    __shared__ float red[4];
    const int s = blockIdx.x;
    const int b = blockIdx.y;
    const int tid = threadIdx.x;
    for (int i = tid; i < 66 * 66; i += 256) (&sm[0][0])[i] = 0.f;
    __syncthreads();
    const int cd = 128 + s;
    {
        const float* ip = pre + ((size_t)b * C3_ + cd) * L_;
        for (int p = tid; p < 4096; p += 256)
            sm[(p >> 6) + 1][(p & 63) + 1] = ip[p];
    }
    __syncthreads();
    float dt[16];
    {
        const float* wp = wdw + cd * 9;
        float w00 = wp[0], w01 = wp[1], w02 = wp[2],
              w10 = wp[3], w11 = wp[4], w12 = wp[5],
              w20 = wp[6], w21 = wp[7], w22 = wp[8];
        float bb = bdw[cd];
        #pragma unroll
        for (int i = 0; i < 16; ++i) {
            int p = tid + 256 * i;
            int yy = p >> 6, xx = p & 63;
            dt[i] = bb
                + sm[yy][xx] * w00     + sm[yy][xx + 1] * w01     + sm[yy][xx + 2] * w02
                + sm[yy + 1][xx] * w10 + sm[yy + 1][xx + 1] * w11 + sm[yy + 1][xx + 2] * w12
                + sm[yy + 2][xx] * w20 + sm[yy + 2][xx + 1] * w21 + sm[yy + 2][xx + 2] * w22;
        }
    }
    float mx = dt[0];
    #pragma unroll
    for (int i = 1; i < 16; ++i) mx = fmaxf(mx, dt[i]);
    #pragma unroll
    for (int off = 32; off >= 1; off >>= 1) mx = fmaxf(mx, __shfl_xor(mx, off, 64));
    if ((tid & 63) == 0) red[tid >> 6] = mx;
    __syncthreads();
    mx = fmaxf(fmaxf(red[0], red[1]), fmaxf(red[2], red[3]));
    float e[16];
    float lsum = 0.f;
    #pragma unroll
    for (int i = 0; i < 16; ++i) { e[i] = expf(dt[i] - mx); lsum += e[i]; }
    #pragma unroll
    for (int off = 32; off >= 1; off >>= 1) lsum += __shfl_xor(lsum, off, 64);
    __syncthreads();
    if ((tid & 63) == 0) red[tid >> 6] = lsum;
    __syncthreads();
    const float inv = 1.f / (red[0] + red[1] + red[2] + red[3]);
    {
        const float* ip = pre + ((size_t)b * C3_ + s) * L_;
        for (int p = tid; p < 4096; p += 256)
            sm[(p >> 6) + 1][(p & 63) + 1] = ip[p];
    }
    __syncthreads();
    {
        const float* wp = wdw + s * 9;
        float w00 = wp[0], w01 = wp[1], w02 = wp[2],
              w10 = wp[3], w11 = wp[4], w12 = wp[5],
              w20 = wp[6], w21 = wp[7], w22 = wp[8];
        float bb = bdw[s];
        float* op = ab + ((size_t)b * S_ + s) * L_;
        #pragma unroll
        for (int i = 0; i < 16; ++i) {
            int p = tid + 256 * i;
            int yy = p >> 6, xx = p & 63;
            float bm = bb
                + sm[yy][xx] * w00     + sm[yy][xx + 1] * w01     + sm[yy][xx + 2] * w02
                + sm[yy + 1][xx] * w10 + sm[yy + 1][xx + 1] * w11 + sm[yy + 1][xx + 2] * w12
                + sm[yy + 2][xx] * w20 + sm[yy + 2][xx + 1] * w21 + sm[yy + 2][xx + 2] * w22;
            op[p] = e[i] * inv * bm;
        }
    }
}

// ---------------------------------------------------------------------------
// K3 (MFMA, no LDS): hp[chunk][b][d][s] += x[b,d,l]*ab[b,s,l] over l-chunk 256
// Both operands are l(K)-contiguous -> direct global->reg bf16 fragments.
// Block: 4 waves in 2x2 (wr: 64 d-rows, wc: 32 s-cols); grid (dtile, b, chunk).
// No barriers, no shared memory -> pure streaming MFMA.
// ---------------------------------------------------------------------------
__global__ __launch_bounds__(256) void k3_hpart_mfma(
    const float* __restrict__ x, const float* __restrict__ ab,
    float* __restrict__ hp)
{
    const int dt    = blockIdx.x;   // 0..1
    const int b     = blockIdx.y;   // 0..31
    const int chunk = blockIdx.z;   // 0..15
    const int tid  = threadIdx.x;
    const int lane = tid & 63;
    const int wv   = tid >> 6;
    const int wr   = wv >> 1, wc = wv & 1;
    const int lm   = lane & 15, kg = lane >> 4;
    const int d_base = dt * 128 + wr * 64;
    const int s_base = wc * 32;
    const float* xb  = x  + (size_t)b * D_ * L_;
    const float* abb = ab + (size_t)b * S_ * L_;

    f32x4 acc[4][2];
    #pragma unroll
    for (int mi = 0; mi < 4; ++mi)
        #pragma unroll
        for (int nj = 0; nj < 2; ++nj)
            acc[mi][nj] = (f32x4){0.f, 0.f, 0.f, 0.f};

    #pragma unroll 2
    for (int ks = 0; ks < 8; ++ks) {
        const int l = chunk * 256 + ks * 32 + kg * 8;
        short8 bfr[2];
        #pragma unroll
        for (int nj = 0; nj < 2; ++nj)
            bfr[nj] = ld_cvt8(abb + (size_t)(s_base + nj * 16 + lm) * L_ + l);
        #pragma unroll
        for (int mi = 0; mi < 4; ++mi) {
            short8 a = ld_cvt8(xb + (size_t)(d_base + mi * 16 + lm) * L_ + l);
            #pragma unroll
            for (int nj = 0; nj < 2; ++nj)
                acc[mi][nj] = __builtin_amdgcn_mfma_f32_16x16x32_bf16(
                    a, bfr[nj], acc[mi][nj], 0, 0, 0);
        }
    }
    float* hpo = hp + (size_t)chunk * HOUTSZ + (size_t)b * D_ * S_;
    #pragma unroll
    for (int mi = 0; mi < 4; ++mi)
        #pragma unroll
        for (int r = 0; r < 4; ++r) {
            int d = d_base + mi * 16 + kg * 4 + r;
            #pragma unroll
            for (int nj = 0; nj < 2; ++nj)
                hpo[(size_t)d * S_ + s_base + nj * 16 + lm] = acc[mi][nj][r];
        }
}

__global__ __launch_bounds__(256) void k3r_reduce(
    const float* __restrict__ hp, float* __restrict__ h)
{
    size_t i = (size_t)blockIdx.x * 256 + threadIdx.x;
    float sum = 0.f;
    #pragma unroll
    for (int c = 0; c < NCHUNK; ++c) sum += hp[(size_t)c * HOUTSZ + i];
    h[i] = sum;
}

// ---------------------------------------------------------------------------
// K4a: hz = w_hz @ h + b_hz; g = h2 * (silu(z) + D)
// ---------------------------------------------------------------------------
__global__ __launch_bounds__(256) void k4a_gate(
    const float* __restrict__ h, const float* __restrict__ whz,
    const float* __restrict__ bhz, const float* __restrict__ Dp,
    float* __restrict__ g)
{
    __shared__ float Ah[16][68];
    __shared__ float Az[16][68];
    __shared__ float Bs[16][64];
    const int o0 = blockIdx.x * 64;
    const int b  = blockIdx.y;
    const int tid = threadIdx.x;
    const int tx = tid & 15, ty = tid >> 4;
    float acch[4][4] = {}, accz[4][4] = {};
    const float* hb = h + (size_t)b * D_ * S_;
    for (int k0 = 0; k0 < D_; k0 += 16) {
        {
            int o = tid & 15, k = tid >> 4;
            #pragma unroll
            for (int i = 0; i < 4; ++i) {
                Ah[k][o + 16 * i] = whz[(size_t)(o0 + o + 16 * i) * D_ + k0 + k];
                Az[k][o + 16 * i] = whz[(size_t)(o0 + o + 16 * i + 256) * D_ + k0 + k];
            }
        }
        {
            int s = tid & 63, k = tid >> 6;
            #pragma unroll
            for (int i = 0; i < 4; ++i)
                Bs[k + 4 * i][s] = hb[(size_t)(k0 + k + 4 * i) * S_ + s];
        }
        __syncthreads();
        #pragma unroll
        for (int k = 0; k < 16; ++k) {
            float ah[4], az[4], bb[4];
            #pragma unroll
            for (int i = 0; i < 4; ++i) { ah[i] = Ah[k][ty * 4 + i]; az[i] = Az[k][ty * 4 + i]; }
            #pragma unroll
            for (int j = 0; j < 4; ++j) bb[j] = Bs[k][tx * 4 + j];
            #pragma unroll
            for (int i = 0; i < 4; ++i)
                #pragma unroll
                for (int j = 0; j < 4; ++j) {
                    acch[i][j] += ah[i] * bb[j];
                    accz[i][j] += az[i] * bb[j];
                }
        }
        __syncthreads();
    }
    const float dp = Dp[0];
    #pragma unroll
    for (int i = 0; i < 4; ++i) {
        int o = o0 + ty * 4 + i;
        float bh = bhz[o], bz = bhz[o + 256];
        #pragma unroll
        for (int j = 0; j < 4; ++j) {
            float h2 = acch[i][j] + bh;
            float z  = accz[i][j] + bz;
            float sil = z / (1.f + expf(-z));
            g[((size_t)b * D_ + o) * S_ + tx * 4 + j] = h2 * (sil + dp);
        }
    }
}

// ---------------------------------------------------------------------------
// K4b: hout = w_out @ g + b_out -> d_out (output 1)
// ---------------------------------------------------------------------------
__global__ __launch_bounds__(256) void k4b_hout(
    const float* __restrict__ g, const float* __restrict__ wout,
    const float* __restrict__ bout, float* __restrict__ hout)
{
    __shared__ float At[16][68];
    __shared__ float Bs[16][64];
    const int o0 = blockIdx.x * 64;
    const int b  = blockIdx.y;
    const int tid = threadIdx.x;
    const int tx = tid & 15, ty = tid >> 4;
    float acc[4][4] = {};
    const float* gb = g + (size_t)b * D_ * S_;
    for (int k0 = 0; k0 < D_; k0 += 16) {
        {
            int o = tid & 15, k = tid >> 4;
            #pragma unroll
            for (int i = 0; i < 4; ++i)
                At[k][o + 16 * i] = wout[(size_t)(o0 + o + 16 * i) * D_ + k0 + k];
        }
        {
            int s = tid & 63, k = tid >> 6;
            #pragma unroll
            for (int i = 0; i < 4; ++i)
                Bs[k + 4 * i][s] = gb[(size_t)(k0 + k + 4 * i) * S_ + s];
        }
        __syncthreads();
        #pragma unroll
        for (int k = 0; k < 16; ++k) {
            float a[4], bb[4];
            #pragma unroll
            for (int i = 0; i < 4; ++i) a[i] = At[k][ty * 4 + i];
            #pragma unroll
            for (int j = 0; j < 4; ++j) bb[j] = Bs[k][tx * 4 + j];
            #pragma unroll
            for (int i = 0; i < 4; ++i)
                #pragma unroll
                for (int j = 0; j < 4; ++j)
                    acc[i][j] += a[i] * bb[j];
        }
        __syncthreads();
    }
    #pragma unroll
    for (int i = 0; i < 4; ++i) {
        int o = o0 + ty * 4 + i;
        float bv = bout[o];
        #pragma unroll
        for (int j = 0; j < 4; ++j)
            hout[((size_t)b * D_ + o) * S_ + tx * 4 + j] = acc[i][j] + bv;
    }
}

// ---------------------------------------------------------------------------
// K5 (MFMA): y[b][d][l] = sum_s hout[b][d][s] * cm[b][s][l]
// ---------------------------------------------------------------------------
__global__ __launch_bounds__(256) void k5_expand_mfma(
    const float* __restrict__ hout, const float* __restrict__ cm,
    float* __restrict__ y)
{
    __shared__ __align__(16) short A_lds[64][72];   // [d][s]
    __shared__ __align__(16) short B_lds[128][72];  // [l][s]
    const int l0 = blockIdx.x * 128;
    const int d0 = blockIdx.y * 64;
    const int b  = blockIdx.z;
    const int tid  = threadIdx.x;
    const int lane = tid & 63;
    const int wv   = tid >> 6;
    const int lm   = lane & 15, kg = lane >> 4;

    #pragma unroll
    for (int q = 0; q < 2; ++q) {
        int task = q * 256 + tid;
        int d = task >> 3, sg = (task & 7) * 8;
        *(short8*)&A_lds[d][sg] = ld_cvt8(hout + ((size_t)b * D_ + d0 + d) * S_ + sg);
    }
    #pragma unroll
    for (int q = 0; q < 4; ++q) {
        int l = tid & 127;
        int sg = (q * 2 + (tid >> 7)) * 8;
        const float* cp = cm + ((size_t)b * S_ + sg) * L_ + l0 + l;
        short8 s;
        #pragma unroll
        for (int r = 0; r < 8; ++r) s[r] = f2bf(cp[(size_t)r * L_]);
        *(short8*)&B_lds[l][sg] = s;
    }
    __syncthreads();

    f32x4 acc[4][2];
    #pragma unroll
    for (int mi = 0; mi < 4; ++mi)
        #pragma unroll
        for (int nj = 0; nj < 2; ++nj)
            acc[mi][nj] = (f32x4){0.f, 0.f, 0.f, 0.f};
    #pragma unroll
    for (int ks = 0; ks < 2; ++ks) {
        short8 bb[2];
        #pragma unroll
        for (int nj = 0; nj < 2; ++nj)
            bb[nj] = *(const short8*)&B_lds[wv * 32 + nj * 16 + lm][ks * 32 + kg * 8];
        #pragma unroll
        for (int mi = 0; mi < 4; ++mi) {
            short8 a = *(const short8*)&A_lds[mi * 16 + lm][ks * 32 + kg * 8];
            #pragma unroll
            for (int nj = 0; nj < 2; ++nj)
                acc[mi][nj] = __builtin_amdgcn_mfma_f32_16x16x32_bf16(
                    a, bb[nj], acc[mi][nj], 0, 0, 0);
        }
    }
    const int col = l0 + wv * 32 + lm;
    #pragma unroll
    for (int mi = 0; mi < 4; ++mi)
        #pragma unroll
        for (int r = 0; r < 4; ++r)
            #pragma unroll
            for (int nj = 0; nj < 2; ++nj)
                y[((size_t)b * D_ + d0 + mi * 16 + kg * 4 + r) * L_ + col + nj * 16]
                    = acc[mi][nj][r];
}

// ---------------------------------------------------------------------------
extern "C" void kernel_launch(void* const* d_in, const int* in_sizes, int n_in,
                              void* d_out, int out_size, void* d_ws, size_t ws_size,
                              hipStream_t stream)
{
    const float* x      = (const float*)d_in[0];
    const float* w_bcdt = (const float*)d_in[3];
    const float* b_bcdt = (const float*)d_in[4];
    const float* w_dw   = (const float*)d_in[5];
    const float* b_dw   = (const float*)d_in[6];
    const float* w_hz   = (const float*)d_in[7];
    const float* b_hz   = (const float*)d_in[8];
    const float* w_out  = (const float*)d_in[9];
    const float* b_out  = (const float*)d_in[10];
    // d_in[11] = A_param: constant along softmax axis L -> cancels, unused
    const float* Dp     = (const float*)d_in[12];

    float* ws  = (float*)d_ws;
    float* pre = ws;                         // 32*192*4096 = 25165824 f
    float* ab  = ws + 25165824;              //  8388608 f
    float* cm  = ab + 8388608;               //  8388608 f
    // pre dead after convs: reuse for hp (16*524288 = 8388608 f) + h + g
    float* hp  = pre;
    float* h   = pre + 8388608;
    float* g   = pre + 8388608 + 524288;

    float* y    = (float*)d_out;
    float* hout = (float*)d_out + YSZ;

    k1_bcdt_mfma  <<<dim3(32, 32),     256, 0, stream>>>(x, w_bcdt, b_bcdt, pre);
    k2a_conv_cm   <<<dim3(64, 32),     256, 0, stream>>>(pre, w_dw, b_dw, cm);
    k2b_softmax_ab<<<dim3(64, 32),     256, 0, stream>>>(pre, w_dw, b_dw, ab);
    k3_hpart_mfma <<<dim3(2, 32, NCHUNK), 256, 0, stream>>>(x, ab, hp);
    k3r_reduce    <<<2048,             256, 0, stream>>>(hp, h);
    k4a_gate      <<<dim3(4, 32),      256, 0, stream>>>(h, w_hz, b_hz, Dp, g);
    k4b_hout      <<<dim3(4, 32),      256, 0, stream>>>(g, w_out, b_out, hout);
    k5_expand_mfma<<<dim3(32, 4, 32),  256, 0, stream>>>(hout, cm, y);
}

// Round 4
// 221.025 us; speedup vs baseline: 2.1085x; 1.1586x over previous
//
#include <hip/hip_runtime.h>
#include <math.h>

#define B_  32
#define D_  256
#define L_  4096
#define S_  64
#define C3_ 192

#define YSZ    ((size_t)B_ * D_ * L_)   /* 33554432 */
#define HOUTSZ ((size_t)B_ * D_ * S_)   /* 524288  */
#define NCHUNK 16

typedef __attribute__((ext_vector_type(8))) short short8;
typedef __attribute__((ext_vector_type(4))) float f32x4;
typedef unsigned short ushort_t;
typedef unsigned int uint_t;

__device__ __forceinline__ short f2bf(float f) {
    unsigned u = __float_as_uint(f);
    u += 0x7fffu + ((u >> 16) & 1u);   // round-to-nearest-even
    return (short)(u >> 16);
}
__device__ __forceinline__ float bf2f(ushort_t u) {
    return __uint_as_float((uint_t)u << 16);
}
__device__ __forceinline__ short8 ld_cvt8(const float* p) {
    const float4* q = reinterpret_cast<const float4*>(p);
    float4 p0 = q[0], p1 = q[1];
    short8 s;
    s[0] = f2bf(p0.x); s[1] = f2bf(p0.y); s[2] = f2bf(p0.z); s[3] = f2bf(p0.w);
    s[4] = f2bf(p1.x); s[5] = f2bf(p1.y); s[6] = f2bf(p1.z); s[7] = f2bf(p1.w);
    return s;
}

// ---------------------------------------------------------------------------
// K1 (MFMA): pre_bf[b][o][l] = bf16( b_bcdt[o] + sum_d w[o][d] * x[b][d][l] )
// ---------------------------------------------------------------------------
__global__ __launch_bounds__(256) void k1_bcdt_mfma(
    const float* __restrict__ x, const float* __restrict__ w,
    const float* __restrict__ bias, ushort_t* __restrict__ out)
{
    __shared__ __align__(16) short A_lds[192][40];  // [o][k]
    __shared__ __align__(16) short B_lds[128][40];  // [l][k]
    const int l0 = blockIdx.x * 128;
    const int b  = blockIdx.y;
    const int tid  = threadIdx.x;
    const int lane = tid & 63;
    const int wv   = tid >> 6;
    const int lm   = lane & 15;
    const int kg   = lane >> 4;
    const float* xb = x + (size_t)b * D_ * L_;

    f32x4 acc[12][2];
    #pragma unroll
    for (int mi = 0; mi < 12; ++mi)
        #pragma unroll
        for (int nj = 0; nj < 2; ++nj)
            acc[mi][nj] = (f32x4){0.f, 0.f, 0.f, 0.f};

    for (int k0 = 0; k0 < D_; k0 += 32) {
        if (k0) __syncthreads();
        #pragma unroll
        for (int q = 0; q < 3; ++q) {
            int task = q * 256 + tid;
            int o = task >> 2, kk = (task & 3) * 8;
            *(short8*)&A_lds[o][kk] = ld_cvt8(w + (size_t)o * D_ + k0 + kk);
        }
        #pragma unroll
        for (int q = 0; q < 2; ++q) {
            int task = q * 256 + tid;
            int l = task & 127, dg = task >> 7;
            const float* xp = xb + (size_t)(k0 + dg * 8) * L_ + l0 + l;
            short8 s;
            #pragma unroll
            for (int r = 0; r < 8; ++r) s[r] = f2bf(xp[(size_t)r * L_]);
            *(short8*)&B_lds[l][dg * 8] = s;
        }
        __syncthreads();
        short8 bb[2];
        #pragma unroll
        for (int nj = 0; nj < 2; ++nj)
            bb[nj] = *(const short8*)&B_lds[wv * 32 + nj * 16 + lm][kg * 8];
        #pragma unroll
        for (int mi = 0; mi < 12; ++mi) {
            short8 a = *(const short8*)&A_lds[mi * 16 + lm][kg * 8];
            #pragma unroll
            for (int nj = 0; nj < 2; ++nj)
                acc[mi][nj] = __builtin_amdgcn_mfma_f32_16x16x32_bf16(
                    a, bb[nj], acc[mi][nj], 0, 0, 0);
        }
    }
    ushort_t* ob = out + (size_t)b * C3_ * L_;
    const int col = l0 + wv * 32 + lm;
    #pragma unroll
    for (int mi = 0; mi < 12; ++mi) {
        #pragma unroll
        for (int r = 0; r < 4; ++r) {
            int o = mi * 16 + kg * 4 + r;
            float bv = bias[o];
            #pragma unroll
            for (int nj = 0; nj < 2; ++nj)
                ob[(size_t)o * L_ + col + nj * 16] =
                    (ushort_t)f2bf(acc[mi][nj][r] + bv);
        }
    }
}

// ---------------------------------------------------------------------------
// K2 fused: blockIdx.x in [0,64)  -> cm channel 64+s  (conv -> cm_bf)
//           blockIdx.x in [64,128)-> ab for s         (conv dt -> softmax -> *conv Bm)
// ---------------------------------------------------------------------------
__global__ __launch_bounds__(256) void k2_conv(
    const ushort_t* __restrict__ pre, const float* __restrict__ wdw,
    const float* __restrict__ bdw, ushort_t* __restrict__ cm,
    ushort_t* __restrict__ ab)
{
    __shared__ float sm[66][66];
    __shared__ float red[4];
    const int t   = blockIdx.x;
    const int b   = blockIdx.y;
    const int s   = t & 63;
    const int tid = threadIdx.x;

    for (int i = tid; i < 66 * 66; i += 256) (&sm[0][0])[i] = 0.f;
    __syncthreads();

    if (t < 64) {
        // ---------------- cm path: channel 64+s ----------------
        const int c = 64 + s;
        const uint_t* ip32 = reinterpret_cast<const uint_t*>(
            pre + ((size_t)b * C3_ + c) * L_);
        for (int p2 = tid; p2 < 2048; p2 += 256) {
            uint_t v = ip32[p2];
            int q = p2 * 2;
            sm[(q >> 6) + 1][(q & 63) + 1] = bf2f((ushort_t)(v & 0xffffu));
            sm[(q >> 6) + 1][(q & 63) + 2] = bf2f((ushort_t)(v >> 16));
        }
        __syncthreads();
        const float* wp = wdw + c * 9;
        float w00 = wp[0], w01 = wp[1], w02 = wp[2],
              w10 = wp[3], w11 = wp[4], w12 = wp[5],
              w20 = wp[6], w21 = wp[7], w22 = wp[8];
        float bb = bdw[c];
        ushort_t* op = cm + ((size_t)b * S_ + s) * L_;
        for (int p = tid; p < 4096; p += 256) {
            int yy = p >> 6, xx = p & 63;
            float v = bb
                + sm[yy][xx] * w00     + sm[yy][xx + 1] * w01     + sm[yy][xx + 2] * w02
                + sm[yy + 1][xx] * w10 + sm[yy + 1][xx + 1] * w11 + sm[yy + 1][xx + 2] * w12
                + sm[yy + 2][xx] * w20 + sm[yy + 2][xx + 1] * w21 + sm[yy + 2][xx + 2] * w22;
            op[p] = (ushort_t)f2bf(v);
        }
        return;
    }

    // ---------------- ab path: dt channel 128+s, Bm channel s ----------------
    const int cd = 128 + s;
    {
        const uint_t* ip32 = reinterpret_cast<const uint_t*>(
            pre + ((size_t)b * C3_ + cd) * L_);
        for (int p2 = tid; p2 < 2048; p2 += 256) {
            uint_t v = ip32[p2];
            int q = p2 * 2;
            sm[(q >> 6) + 1][(q & 63) + 1] = bf2f((ushort_t)(v & 0xffffu));
            sm[(q >> 6) + 1][(q & 63) + 2] = bf2f((ushort_t)(v >> 16));
        }
    }
    __syncthreads();
    float dt[16];
    {
        const float* wp = wdw + cd * 9;
        float w00 = wp[0], w01 = wp[1], w02 = wp[2],
              w10 = wp[3], w11 = wp[4], w12 = wp[5],
              w20 = wp[6], w21 = wp[7], w22 = wp[8];
        float bb = bdw[cd];
        #pragma unroll
        for (int i = 0; i < 16; ++i) {
            int p = tid + 256 * i;
            int yy = p >> 6, xx = p & 63;
            dt[i] = bb
                + sm[yy][xx] * w00     + sm[yy][xx + 1] * w01     + sm[yy][xx + 2] * w02
                + sm[yy + 1][xx] * w10 + sm[yy + 1][xx + 1] * w11 + sm[yy + 1][xx + 2] * w12
                + sm[yy + 2][xx] * w20 + sm[yy + 2][xx + 1] * w21 + sm[yy + 2][xx + 2] * w22;
        }
    }
    float mx = dt[0];
    #pragma unroll
    for (int i = 1; i < 16; ++i) mx = fmaxf(mx, dt[i]);
    #pragma unroll
    for (int off = 32; off >= 1; off >>= 1) mx = fmaxf(mx, __shfl_xor(mx, off, 64));
    if ((tid & 63) == 0) red[tid >> 6] = mx;
    __syncthreads();
    mx = fmaxf(fmaxf(red[0], red[1]), fmaxf(red[2], red[3]));
    float e[16];
    float lsum = 0.f;
    #pragma unroll
    for (int i = 0; i < 16; ++i) { e[i] = expf(dt[i] - mx); lsum += e[i]; }
    #pragma unroll
    for (int off = 32; off >= 1; off >>= 1) lsum += __shfl_xor(lsum, off, 64);
    __syncthreads();
    if ((tid & 63) == 0) red[tid >> 6] = lsum;
    __syncthreads();
    const float inv = 1.f / (red[0] + red[1] + red[2] + red[3]);
    {
        const uint_t* ip32 = reinterpret_cast<const uint_t*>(
            pre + ((size_t)b * C3_ + s) * L_);
        for (int p2 = tid; p2 < 2048; p2 += 256) {
            uint_t v = ip32[p2];
            int q = p2 * 2;
            sm[(q >> 6) + 1][(q & 63) + 1] = bf2f((ushort_t)(v & 0xffffu));
            sm[(q >> 6) + 1][(q & 63) + 2] = bf2f((ushort_t)(v >> 16));
        }
    }
    __syncthreads();
    {
        const float* wp = wdw + s * 9;
        float w00 = wp[0], w01 = wp[1], w02 = wp[2],
              w10 = wp[3], w11 = wp[4], w12 = wp[5],
              w20 = wp[6], w21 = wp[7], w22 = wp[8];
        float bb = bdw[s];
        ushort_t* op = ab + ((size_t)b * S_ + s) * L_;
        #pragma unroll
        for (int i = 0; i < 16; ++i) {
            int p = tid + 256 * i;
            int yy = p >> 6, xx = p & 63;
            float bm = bb
                + sm[yy][xx] * w00     + sm[yy][xx + 1] * w01     + sm[yy][xx + 2] * w02
                + sm[yy + 1][xx] * w10 + sm[yy + 1][xx + 1] * w11 + sm[yy + 1][xx + 2] * w12
                + sm[yy + 2][xx] * w20 + sm[yy + 2][xx + 1] * w21 + sm[yy + 2][xx + 2] * w22;
            op[p] = (ushort_t)f2bf(e[i] * inv * bm);
        }
    }
}

// ---------------------------------------------------------------------------
// K3 (MFMA, no LDS): hp[chunk][b][d][s] += x[b,d,l]*ab[b,s,l] over l-chunk 256
// ab is bf16 -> direct 16-B fragment loads; x is f32 -> ld_cvt8.
// ---------------------------------------------------------------------------
__global__ __launch_bounds__(256) void k3_hpart_mfma(
    const float* __restrict__ x, const ushort_t* __restrict__ ab,
    float* __restrict__ hp)
{
    const int dt    = blockIdx.x;   // 0..1
    const int b     = blockIdx.y;   // 0..31
    const int chunk = blockIdx.z;   // 0..15
    const int tid  = threadIdx.x;
    const int lane = tid & 63;
    const int wv   = tid >> 6;
    const int wr   = wv >> 1, wc = wv & 1;
    const int lm   = lane & 15, kg = lane >> 4;
    const int d_base = dt * 128 + wr * 64;
    const int s_base = wc * 32;
    const float*    xb  = x  + (size_t)b * D_ * L_;
    const ushort_t* abb = ab + (size_t)b * S_ * L_;

    f32x4 acc[4][2];
    #pragma unroll
    for (int mi = 0; mi < 4; ++mi)
        #pragma unroll
        for (int nj = 0; nj < 2; ++nj)
            acc[mi][nj] = (f32x4){0.f, 0.f, 0.f, 0.f};

    #pragma unroll 2
    for (int ks = 0; ks < 8; ++ks) {
        const int l = chunk * 256 + ks * 32 + kg * 8;
        short8 bfr[2];
        #pragma unroll
        for (int nj = 0; nj < 2; ++nj)
            bfr[nj] = *reinterpret_cast<const short8*>(
                abb + (size_t)(s_base + nj * 16 + lm) * L_ + l);
        #pragma unroll
        for (int mi = 0; mi < 4; ++mi) {
            short8 a = ld_cvt8(xb + (size_t)(d_base + mi * 16 + lm) * L_ + l);
            #pragma unroll
            for (int nj = 0; nj < 2; ++nj)
                acc[mi][nj] = __builtin_amdgcn_mfma_f32_16x16x32_bf16(
                    a, bfr[nj], acc[mi][nj], 0, 0, 0);
        }
    }
    float* hpo = hp + (size_t)chunk * HOUTSZ + (size_t)b * D_ * S_;
    #pragma unroll
    for (int mi = 0; mi < 4; ++mi)
        #pragma unroll
        for (int r = 0; r < 4; ++r) {
            int d = d_base + mi * 16 + kg * 4 + r;
            #pragma unroll
            for (int nj = 0; nj < 2; ++nj)
                hpo[(size_t)d * S_ + s_base + nj * 16 + lm] = acc[mi][nj][r];
        }
}

// ---------------------------------------------------------------------------
// K4a: h = sum_chunk hp (fused into staging); hz = w_hz @ h + b_hz;
//      g = h2 * (silu(z) + D)
// ---------------------------------------------------------------------------
__global__ __launch_bounds__(256) void k4a_gate(
    const float* __restrict__ hp, const float* __restrict__ whz,
    const float* __restrict__ bhz, const float* __restrict__ Dp,
    float* __restrict__ g)
{
    __shared__ float Ah[16][68];
    __shared__ float Az[16][68];
    __shared__ float Bs[16][64];
    const int o0 = blockIdx.x * 64;
    const int b  = blockIdx.y;
    const int tid = threadIdx.x;
    const int tx = tid & 15, ty = tid >> 4;
    float acch[4][4] = {}, accz[4][4] = {};
    const float* hb = hp + (size_t)b * D_ * S_;
    for (int k0 = 0; k0 < D_; k0 += 16) {
        {
            int o = tid & 15, k = tid >> 4;
            #pragma unroll
            for (int i = 0; i < 4; ++i) {
                Ah[k][o + 16 * i] = whz[(size_t)(o0 + o + 16 * i) * D_ + k0 + k];
                Az[k][o + 16 * i] = whz[(size_t)(o0 + o + 16 * i + 256) * D_ + k0 + k];
            }
        }
        {
            int s = tid & 63, k = tid >> 6;
            #pragma unroll
            for (int i = 0; i < 4; ++i) {
                float sum = 0.f;
                #pragma unroll
                for (int c = 0; c < NCHUNK; ++c)
                    sum += hb[(size_t)c * HOUTSZ + (size_t)(k0 + k + 4 * i) * S_ + s];
                Bs[k + 4 * i][s] = sum;
            }
        }
        __syncthreads();
        #pragma unroll
        for (int k = 0; k < 16; ++k) {
            float ah[4], az[4], bb[4];
            #pragma unroll
            for (int i = 0; i < 4; ++i) { ah[i] = Ah[k][ty * 4 + i]; az[i] = Az[k][ty * 4 + i]; }
            #pragma unroll
            for (int j = 0; j < 4; ++j) bb[j] = Bs[k][tx * 4 + j];
            #pragma unroll
            for (int i = 0; i < 4; ++i)
                #pragma unroll
                for (int j = 0; j < 4; ++j) {
                    acch[i][j] += ah[i] * bb[j];
                    accz[i][j] += az[i] * bb[j];
                }
        }
        __syncthreads();
    }
    const float dp = Dp[0];
    #pragma unroll
    for (int i = 0; i < 4; ++i) {
        int o = o0 + ty * 4 + i;
        float bh = bhz[o], bz = bhz[o + 256];
        #pragma unroll
        for (int j = 0; j < 4; ++j) {
            float h2 = acch[i][j] + bh;
            float z  = accz[i][j] + bz;
            float sil = z / (1.f + expf(-z));
            g[((size_t)b * D_ + o) * S_ + tx * 4 + j] = h2 * (sil + dp);
        }
    }
}

// ---------------------------------------------------------------------------
// K4b: hout = w_out @ g + b_out -> d_out (output 1)
// ---------------------------------------------------------------------------
__global__ __launch_bounds__(256) void k4b_hout(
    const float* __restrict__ g, const float* __restrict__ wout,
    const float* __restrict__ bout, float* __restrict__ hout)
{
    __shared__ float At[16][68];
    __shared__ float Bs[16][64];
    const int o0 = blockIdx.x * 64;
    const int b  = blockIdx.y;
    const int tid = threadIdx.x;
    const int tx = tid & 15, ty = tid >> 4;
    float acc[4][4] = {};
    const float* gb = g + (size_t)b * D_ * S_;
    for (int k0 = 0; k0 < D_; k0 += 16) {
        {
            int o = tid & 15, k = tid >> 4;
            #pragma unroll
            for (int i = 0; i < 4; ++i)
                At[k][o + 16 * i] = wout[(size_t)(o0 + o + 16 * i) * D_ + k0 + k];
        }
        {
            int s = tid & 63, k = tid >> 6;
            #pragma unroll
            for (int i = 0; i < 4; ++i)
                Bs[k + 4 * i][s] = gb[(size_t)(k0 + k + 4 * i) * S_ + s];
        }
        __syncthreads();
        #pragma unroll
        for (int k = 0; k < 16; ++k) {
            float a[4], bb[4];
            #pragma unroll
            for (int i = 0; i < 4; ++i) a[i] = At[k][ty * 4 + i];
            #pragma unroll
            for (int j = 0; j < 4; ++j) bb[j] = Bs[k][tx * 4 + j];
            #pragma unroll
            for (int i = 0; i < 4; ++i)
                #pragma unroll
                for (int j = 0; j < 4; ++j)
                    acc[i][j] += a[i] * bb[j];
        }
        __syncthreads();
    }
    #pragma unroll
    for (int i = 0; i < 4; ++i) {
        int o = o0 + ty * 4 + i;
        float bv = bout[o];
        #pragma unroll
        for (int j = 0; j < 4; ++j)
            hout[((size_t)b * D_ + o) * S_ + tx * 4 + j] = acc[i][j] + bv;
    }
}

// ---------------------------------------------------------------------------
// K5 (MFMA): y[b][d][l] = sum_s hout[b][d][s] * cm_bf[b][s][l]
// ---------------------------------------------------------------------------
__global__ __launch_bounds__(256) void k5_expand_mfma(
    const float* __restrict__ hout, const ushort_t* __restrict__ cm,
    float* __restrict__ y)
{
    __shared__ __align__(16) short A_lds[64][72];   // [d][s]
    __shared__ __align__(16) short B_lds[128][72];  // [l][s]
    const int l0 = blockIdx.x * 128;
    const int d0 = blockIdx.y * 64;
    const int b  = blockIdx.z;
    const int tid  = threadIdx.x;
    const int lane = tid & 63;
    const int wv   = tid >> 6;
    const int lm   = lane & 15, kg = lane >> 4;

    #pragma unroll
    for (int q = 0; q < 2; ++q) {
        int task = q * 256 + tid;
        int d = task >> 3, sg = (task & 7) * 8;
        *(short8*)&A_lds[d][sg] = ld_cvt8(hout + ((size_t)b * D_ + d0 + d) * S_ + sg);
    }
    #pragma unroll
    for (int q = 0; q < 4; ++q) {
        int l = tid & 127;
        int sg = (q * 2 + (tid >> 7)) * 8;
        const ushort_t* cp = cm + ((size_t)b * S_ + sg) * L_ + l0 + l;
        short8 s;
        #pragma unroll
        for (int r = 0; r < 8; ++r) s[r] = (short)cp[(size_t)r * L_];
        *(short8*)&B_lds[l][sg] = s;
    }
    __syncthreads();

    f32x4 acc[4][2];
    #pragma unroll
    for (int mi = 0; mi < 4; ++mi)
        #pragma unroll
        for (int nj = 0; nj < 2; ++nj)
            acc[mi][nj] = (f32x4){0.f, 0.f, 0.f, 0.f};
    #pragma unroll
    for (int ks = 0; ks < 2; ++ks) {
        short8 bb[2];
        #pragma unroll
        for (int nj = 0; nj < 2; ++nj)
            bb[nj] = *(const short8*)&B_lds[wv * 32 + nj * 16 + lm][ks * 32 + kg * 8];
        #pragma unroll
        for (int mi = 0; mi < 4; ++mi) {
            short8 a = *(const short8*)&A_lds[mi * 16 + lm][ks * 32 + kg * 8];
            #pragma unroll
            for (int nj = 0; nj < 2; ++nj)
                acc[mi][nj] = __builtin_amdgcn_mfma_f32_16x16x32_bf16(
                    a, bb[nj], acc[mi][nj], 0, 0, 0);
        }
    }
    const int col = l0 + wv * 32 + lm;
    #pragma unroll
    for (int mi = 0; mi < 4; ++mi)
        #pragma unroll
        for (int r = 0; r < 4; ++r)
            #pragma unroll
            for (int nj = 0; nj < 2; ++nj)
                y[((size_t)b * D_ + d0 + mi * 16 + kg * 4 + r) * L_ + col + nj * 16]
                    = acc[mi][nj][r];
}

// ---------------------------------------------------------------------------
extern "C" void kernel_launch(void* const* d_in, const int* in_sizes, int n_in,
                              void* d_out, int out_size, void* d_ws, size_t ws_size,
                              hipStream_t stream)
{
    const float* x      = (const float*)d_in[0];
    const float* w_bcdt = (const float*)d_in[3];
    const float* b_bcdt = (const float*)d_in[4];
    const float* w_dw   = (const float*)d_in[5];
    const float* b_dw   = (const float*)d_in[6];
    const float* w_hz   = (const float*)d_in[7];
    const float* b_hz   = (const float*)d_in[8];
    const float* w_out  = (const float*)d_in[9];
    const float* b_out  = (const float*)d_in[10];
    // d_in[11] = A_param: constant along softmax axis L -> cancels, unused
    const float* Dp     = (const float*)d_in[12];

    char* base = (char*)d_ws;
    ushort_t* pre_bf = (ushort_t*)(base);                    // 25165824 u16 = 50.3 MB
    ushort_t* ab_bf  = (ushort_t*)(base + 50331648);         //  8388608 u16 = 16.8 MB
    ushort_t* cm_bf  = (ushort_t*)(base + 67108864);         //  8388608 u16 = 16.8 MB
    float*    hp     = (float*)   (base + 83886080);         // 16*524288 f  = 33.5 MB
    float*    g      = (float*)   (base + 117440512);        //   524288 f

    float* y    = (float*)d_out;
    float* hout = (float*)d_out + YSZ;

    k1_bcdt_mfma  <<<dim3(32, 32),        256, 0, stream>>>(x, w_bcdt, b_bcdt, pre_bf);
    k2_conv       <<<dim3(128, 32),       256, 0, stream>>>(pre_bf, w_dw, b_dw, cm_bf, ab_bf);
    k3_hpart_mfma <<<dim3(2, 32, NCHUNK), 256, 0, stream>>>(x, ab_bf, hp);
    k4a_gate      <<<dim3(4, 32),         256, 0, stream>>>(hp, w_hz, b_hz, Dp, g);
    k4b_hout      <<<dim3(4, 32),         256, 0, stream>>>(g, w_out, b_out, hout);
    k5_expand_mfma<<<dim3(32, 4, 32),     256, 0, stream>>>(hout, cm_bf, y);
}

// Round 5
// 212.530 us; speedup vs baseline: 2.1928x; 1.0400x over previous
//
#include <hip/hip_runtime.h>
#include <math.h>

#define B_  32
#define D_  256
#define L_  4096
#define S_  64
#define C3_ 192

#define YSZ    ((size_t)B_ * D_ * L_)   /* 33554432 */
#define HOUTSZ ((size_t)B_ * D_ * S_)   /* 524288  */
#define NCHUNK 8

typedef __attribute__((ext_vector_type(8))) short short8;
typedef __attribute__((ext_vector_type(4))) float f32x4;
typedef unsigned short ushort_t;
typedef unsigned int uint_t;

// hardware bf16 convert (RNE): compiler packs pairs into v_cvt_pk_bf16_f32
__device__ __forceinline__ short f2bf(float f) {
    __bf16 h = (__bf16)f;
    return __builtin_bit_cast(short, h);
}
__device__ __forceinline__ float bf2f(ushort_t u) {
    return __uint_as_float((uint_t)u << 16);
}
__device__ __forceinline__ short8 ld_cvt8(const float* p) {
    const float4* q = reinterpret_cast<const float4*>(p);
    float4 p0 = q[0], p1 = q[1];
    short8 s;
    s[0] = f2bf(p0.x); s[1] = f2bf(p0.y); s[2] = f2bf(p0.z); s[3] = f2bf(p0.w);
    s[4] = f2bf(p1.x); s[5] = f2bf(p1.y); s[6] = f2bf(p1.z); s[7] = f2bf(p1.w);
    return s;
}

// ---------------------------------------------------------------------------
// K1 (MFMA): pre_bf[b][o][l] = bf16( b_bcdt[o] + sum_d w[o][d] * x[b][d][l] )
// B-staging via float2 loads (half the VMEM instructions of scalar dword).
// ---------------------------------------------------------------------------
__global__ __launch_bounds__(256) void k1_bcdt_mfma(
    const float* __restrict__ x, const float* __restrict__ w,
    const float* __restrict__ bias, ushort_t* __restrict__ out)
{
    __shared__ __align__(16) short A_lds[192][40];  // [o][k]
    __shared__ __align__(16) short B_lds[128][40];  // [l][k]
    const int l0 = blockIdx.x * 128;
    const int b  = blockIdx.y;
    const int tid  = threadIdx.x;
    const int lane = tid & 63;
    const int wv   = tid >> 6;
    const int lm   = lane & 15;
    const int kg   = lane >> 4;
    const float* xb = x + (size_t)b * D_ * L_;

    f32x4 acc[12][2];
    #pragma unroll
    for (int mi = 0; mi < 12; ++mi)
        #pragma unroll
        for (int nj = 0; nj < 2; ++nj)
            acc[mi][nj] = (f32x4){0.f, 0.f, 0.f, 0.f};

    for (int k0 = 0; k0 < D_; k0 += 32) {
        if (k0) __syncthreads();
        // ---- stage A: w[0..192)[k0..k0+32) ----
        #pragma unroll
        for (int q = 0; q < 3; ++q) {
            int task = q * 256 + tid;
            int o = task >> 2, kk = (task & 3) * 8;
            *(short8*)&A_lds[o][kk] = ld_cvt8(w + (size_t)o * D_ + k0 + kk);
        }
        // ---- stage B: x[k0..k0+32)[l0..l0+128) -> [l][k], float2 loads ----
        {
            int lp = tid & 63;            // l-pair
            int kgs = tid >> 6;           // k-group of 8
            const float* xp = xb + (size_t)(k0 + kgs * 8) * L_ + l0 + lp * 2;
            float2 v[8];
            #pragma unroll
            for (int r = 0; r < 8; ++r)
                v[r] = *reinterpret_cast<const float2*>(xp + (size_t)r * L_);
            short8 s0, s1;
            #pragma unroll
            for (int r = 0; r < 8; ++r) { s0[r] = f2bf(v[r].x); s1[r] = f2bf(v[r].y); }
            *(short8*)&B_lds[lp * 2][kgs * 8]     = s0;
            *(short8*)&B_lds[lp * 2 + 1][kgs * 8] = s1;
        }
        __syncthreads();
        short8 bb[2];
        #pragma unroll
        for (int nj = 0; nj < 2; ++nj)
            bb[nj] = *(const short8*)&B_lds[wv * 32 + nj * 16 + lm][kg * 8];
        #pragma unroll
        for (int mi = 0; mi < 12; ++mi) {
            short8 a = *(const short8*)&A_lds[mi * 16 + lm][kg * 8];
            #pragma unroll
            for (int nj = 0; nj < 2; ++nj)
                acc[mi][nj] = __builtin_amdgcn_mfma_f32_16x16x32_bf16(
                    a, bb[nj], acc[mi][nj], 0, 0, 0);
        }
    }
    ushort_t* ob = out + (size_t)b * C3_ * L_;
    const int col = l0 + wv * 32 + lm;
    #pragma unroll
    for (int mi = 0; mi < 12; ++mi) {
        #pragma unroll
        for (int r = 0; r < 4; ++r) {
            int o = mi * 16 + kg * 4 + r;
            float bv = bias[o];
            #pragma unroll
            for (int nj = 0; nj < 2; ++nj)
                ob[(size_t)o * L_ + col + nj * 16] =
                    (ushort_t)f2bf(acc[mi][nj][r] + bv);
        }
    }
}

// ---------------------------------------------------------------------------
// K2 fused: blockIdx.x in [0,64)  -> cm channel 64+s  (conv -> cm_bf)
//           blockIdx.x in [64,128)-> ab for s (conv dt -> softmax -> *conv Bm)
// ---------------------------------------------------------------------------
__global__ __launch_bounds__(256) void k2_conv(
    const ushort_t* __restrict__ pre, const float* __restrict__ wdw,
    const float* __restrict__ bdw, ushort_t* __restrict__ cm,
    ushort_t* __restrict__ ab)
{
    __shared__ float sm[66][66];
    __shared__ float red[4];
    const int t   = blockIdx.x;
    const int b   = blockIdx.y;
    const int s   = t & 63;
    const int tid = threadIdx.x;

    for (int i = tid; i < 66 * 66; i += 256) (&sm[0][0])[i] = 0.f;
    __syncthreads();

    if (t < 64) {
        const int c = 64 + s;
        const uint_t* ip32 = reinterpret_cast<const uint_t*>(
            pre + ((size_t)b * C3_ + c) * L_);
        for (int p2 = tid; p2 < 2048; p2 += 256) {
            uint_t v = ip32[p2];
            int q = p2 * 2;
            sm[(q >> 6) + 1][(q & 63) + 1] = bf2f((ushort_t)(v & 0xffffu));
            sm[(q >> 6) + 1][(q & 63) + 2] = bf2f((ushort_t)(v >> 16));
        }
        __syncthreads();
        const float* wp = wdw + c * 9;
        float w00 = wp[0], w01 = wp[1], w02 = wp[2],
              w10 = wp[3], w11 = wp[4], w12 = wp[5],
              w20 = wp[6], w21 = wp[7], w22 = wp[8];
        float bb = bdw[c];
        ushort_t* op = cm + ((size_t)b * S_ + s) * L_;
        for (int p = tid; p < 4096; p += 256) {
            int yy = p >> 6, xx = p & 63;
            float v = bb
                + sm[yy][xx] * w00     + sm[yy][xx + 1] * w01     + sm[yy][xx + 2] * w02
                + sm[yy + 1][xx] * w10 + sm[yy + 1][xx + 1] * w11 + sm[yy + 1][xx + 2] * w12
                + sm[yy + 2][xx] * w20 + sm[yy + 2][xx + 1] * w21 + sm[yy + 2][xx + 2] * w22;
            op[p] = (ushort_t)f2bf(v);
        }
        return;
    }

    const int cd = 128 + s;
    {
        const uint_t* ip32 = reinterpret_cast<const uint_t*>(
            pre + ((size_t)b * C3_ + cd) * L_);
        for (int p2 = tid; p2 < 2048; p2 += 256) {
            uint_t v = ip32[p2];
            int q = p2 * 2;
            sm[(q >> 6) + 1][(q & 63) + 1] = bf2f((ushort_t)(v & 0xffffu));
            sm[(q >> 6) + 1][(q & 63) + 2] = bf2f((ushort_t)(v >> 16));
        }
    }
    __syncthreads();
    float dt[16];
    {
        const float* wp = wdw + cd * 9;
        float w00 = wp[0], w01 = wp[1], w02 = wp[2],
              w10 = wp[3], w11 = wp[4], w12 = wp[5],
              w20 = wp[6], w21 = wp[7], w22 = wp[8];
        float bb = bdw[cd];
        #pragma unroll
        for (int i = 0; i < 16; ++i) {
            int p = tid + 256 * i;
            int yy = p >> 6, xx = p & 63;
            dt[i] = bb
                + sm[yy][xx] * w00     + sm[yy][xx + 1] * w01     + sm[yy][xx + 2] * w02
                + sm[yy + 1][xx] * w10 + sm[yy + 1][xx + 1] * w11 + sm[yy + 1][xx + 2] * w12
                + sm[yy + 2][xx] * w20 + sm[yy + 2][xx + 1] * w21 + sm[yy + 2][xx + 2] * w22;
        }
    }
    float mx = dt[0];
    #pragma unroll
    for (int i = 1; i < 16; ++i) mx = fmaxf(mx, dt[i]);
    #pragma unroll
    for (int off = 32; off >= 1; off >>= 1) mx = fmaxf(mx, __shfl_xor(mx, off, 64));
    if ((tid & 63) == 0) red[tid >> 6] = mx;
    __syncthreads();
    mx = fmaxf(fmaxf(red[0], red[1]), fmaxf(red[2], red[3]));
    float e[16];
    float lsum = 0.f;
    #pragma unroll
    for (int i = 0; i < 16; ++i) { e[i] = expf(dt[i] - mx); lsum += e[i]; }
    #pragma unroll
    for (int off = 32; off >= 1; off >>= 1) lsum += __shfl_xor(lsum, off, 64);
    __syncthreads();
    if ((tid & 63) == 0) red[tid >> 6] = lsum;
    __syncthreads();
    const float inv = 1.f / (red[0] + red[1] + red[2] + red[3]);
    {
        const uint_t* ip32 = reinterpret_cast<const uint_t*>(
            pre + ((size_t)b * C3_ + s) * L_);
        for (int p2 = tid; p2 < 2048; p2 += 256) {
            uint_t v = ip32[p2];
            int q = p2 * 2;
            sm[(q >> 6) + 1][(q & 63) + 1] = bf2f((ushort_t)(v & 0xffffu));
            sm[(q >> 6) + 1][(q & 63) + 2] = bf2f((ushort_t)(v >> 16));
        }
    }
    __syncthreads();
    {
        const float* wp = wdw + s * 9;
        float w00 = wp[0], w01 = wp[1], w02 = wp[2],
              w10 = wp[3], w11 = wp[4], w12 = wp[5],
              w20 = wp[6], w21 = wp[7], w22 = wp[8];
        float bb = bdw[s];
        ushort_t* op = ab + ((size_t)b * S_ + s) * L_;
        #pragma unroll
        for (int i = 0; i < 16; ++i) {
            int p = tid + 256 * i;
            int yy = p >> 6, xx = p & 63;
            float bm = bb
                + sm[yy][xx] * w00     + sm[yy][xx + 1] * w01     + sm[yy][xx + 2] * w02
                + sm[yy + 1][xx] * w10 + sm[yy + 1][xx + 1] * w11 + sm[yy + 1][xx + 2] * w12
                + sm[yy + 2][xx] * w20 + sm[yy + 2][xx + 1] * w21 + sm[yy + 2][xx + 2] * w22;
            op[p] = (ushort_t)f2bf(e[i] * inv * bm);
        }
    }
}

// ---------------------------------------------------------------------------
// K3 (MFMA, no LDS): hp[chunk][b][d][s] += x[b,d,l]*ab[b,s,l] over l-chunk 512
// ---------------------------------------------------------------------------
__global__ __launch_bounds__(256) void k3_hpart_mfma(
    const float* __restrict__ x, const ushort_t* __restrict__ ab,
    float* __restrict__ hp)
{
    const int dt    = blockIdx.x;   // 0..1
    const int b     = blockIdx.y;   // 0..31
    const int chunk = blockIdx.z;   // 0..NCHUNK-1
    const int tid  = threadIdx.x;
    const int lane = tid & 63;
    const int wv   = tid >> 6;
    const int wr   = wv >> 1, wc = wv & 1;
    const int lm   = lane & 15, kg = lane >> 4;
    const int d_base = dt * 128 + wr * 64;
    const int s_base = wc * 32;
    const float*    xb  = x  + (size_t)b * D_ * L_;
    const ushort_t* abb = ab + (size_t)b * S_ * L_;

    f32x4 acc[4][2];
    #pragma unroll
    for (int mi = 0; mi < 4; ++mi)
        #pragma unroll
        for (int nj = 0; nj < 2; ++nj)
            acc[mi][nj] = (f32x4){0.f, 0.f, 0.f, 0.f};

    #pragma unroll 2
    for (int ks = 0; ks < 16; ++ks) {
        const int l = chunk * 512 + ks * 32 + kg * 8;
        short8 bfr[2];
        #pragma unroll
        for (int nj = 0; nj < 2; ++nj)
            bfr[nj] = *reinterpret_cast<const short8*>(
                abb + (size_t)(s_base + nj * 16 + lm) * L_ + l);
        #pragma unroll
        for (int mi = 0; mi < 4; ++mi) {
            short8 a = ld_cvt8(xb + (size_t)(d_base + mi * 16 + lm) * L_ + l);
            #pragma unroll
            for (int nj = 0; nj < 2; ++nj)
                acc[mi][nj] = __builtin_amdgcn_mfma_f32_16x16x32_bf16(
                    a, bfr[nj], acc[mi][nj], 0, 0, 0);
        }
    }
    float* hpo = hp + (size_t)chunk * HOUTSZ + (size_t)b * D_ * S_;
    #pragma unroll
    for (int mi = 0; mi < 4; ++mi)
        #pragma unroll
        for (int r = 0; r < 4; ++r) {
            int d = d_base + mi * 16 + kg * 4 + r;
            #pragma unroll
            for (int nj = 0; nj < 2; ++nj)
                hpo[(size_t)d * S_ + s_base + nj * 16 + lm] = acc[mi][nj][r];
        }
}

// ---------------------------------------------------------------------------
// K4a: h = sum_chunk hp (fused); hz = w_hz @ h + b_hz; g = h2*(silu(z)+D)
// ---------------------------------------------------------------------------
__global__ __launch_bounds__(256) void k4a_gate(
    const float* __restrict__ hp, const float* __restrict__ whz,
    const float* __restrict__ bhz, const float* __restrict__ Dp,
    float* __restrict__ g)
{
    __shared__ float Ah[16][68];
    __shared__ float Az[16][68];
    __shared__ float Bs[16][64];
    const int o0 = blockIdx.x * 64;
    const int b  = blockIdx.y;
    const int tid = threadIdx.x;
    const int tx = tid & 15, ty = tid >> 4;
    float acch[4][4] = {}, accz[4][4] = {};
    const float* hb = hp + (size_t)b * D_ * S_;
    for (int k0 = 0; k0 < D_; k0 += 16) {
        {
            int o = tid & 15, k = tid >> 4;
            #pragma unroll
            for (int i = 0; i < 4; ++i) {
                Ah[k][o + 16 * i] = whz[(size_t)(o0 + o + 16 * i) * D_ + k0 + k];
                Az[k][o + 16 * i] = whz[(size_t)(o0 + o + 16 * i + 256) * D_ + k0 + k];
            }
        }
        {
            int s = tid & 63, k = tid >> 6;
            #pragma unroll
            for (int i = 0; i < 4; ++i) {
                float sum = 0.f;
                #pragma unroll
                for (int c = 0; c < NCHUNK; ++c)
                    sum += hb[(size_t)c * HOUTSZ + (size_t)(k0 + k + 4 * i) * S_ + s];
                Bs[k + 4 * i][s] = sum;
            }
        }
        __syncthreads();
        #pragma unroll
        for (int k = 0; k < 16; ++k) {
            float ah[4], az[4], bb[4];
            #pragma unroll
            for (int i = 0; i < 4; ++i) { ah[i] = Ah[k][ty * 4 + i]; az[i] = Az[k][ty * 4 + i]; }
            #pragma unroll
            for (int j = 0; j < 4; ++j) bb[j] = Bs[k][tx * 4 + j];
            #pragma unroll
            for (int i = 0; i < 4; ++i)
                #pragma unroll
                for (int j = 0; j < 4; ++j) {
                    acch[i][j] += ah[i] * bb[j];
                    accz[i][j] += az[i] * bb[j];
                }
        }
        __syncthreads();
    }
    const float dp = Dp[0];
    #pragma unroll
    for (int i = 0; i < 4; ++i) {
        int o = o0 + ty * 4 + i;
        float bh = bhz[o], bz = bhz[o + 256];
        #pragma unroll
        for (int j = 0; j < 4; ++j) {
            float h2 = acch[i][j] + bh;
            float z  = accz[i][j] + bz;
            float sil = z / (1.f + expf(-z));
            g[((size_t)b * D_ + o) * S_ + tx * 4 + j] = h2 * (sil + dp);
        }
    }
}

// ---------------------------------------------------------------------------
// K4b: hout = w_out @ g + b_out -> d_out (output 1)
// ---------------------------------------------------------------------------
__global__ __launch_bounds__(256) void k4b_hout(
    const float* __restrict__ g, const float* __restrict__ wout,
    const float* __restrict__ bout, float* __restrict__ hout)
{
    __shared__ float At[16][68];
    __shared__ float Bs[16][64];
    const int o0 = blockIdx.x * 64;
    const int b  = blockIdx.y;
    const int tid = threadIdx.x;
    const int tx = tid & 15, ty = tid >> 4;
    float acc[4][4] = {};
    const float* gb = g + (size_t)b * D_ * S_;
    for (int k0 = 0; k0 < D_; k0 += 16) {
        {
            int o = tid & 15, k = tid >> 4;
            #pragma unroll
            for (int i = 0; i < 4; ++i)
                At[k][o + 16 * i] = wout[(size_t)(o0 + o + 16 * i) * D_ + k0 + k];
        }
        {
            int s = tid & 63, k = tid >> 6;
            #pragma unroll
            for (int i = 0; i < 4; ++i)
                Bs[k + 4 * i][s] = gb[(size_t)(k0 + k + 4 * i) * S_ + s];
        }
        __syncthreads();
        #pragma unroll
        for (int k = 0; k < 16; ++k) {
            float a[4], bb[4];
            #pragma unroll
            for (int i = 0; i < 4; ++i) a[i] = At[k][ty * 4 + i];
            #pragma unroll
            for (int j = 0; j < 4; ++j) bb[j] = Bs[k][tx * 4 + j];
            #pragma unroll
            for (int i = 0; i < 4; ++i)
                #pragma unroll
                for (int j = 0; j < 4; ++j)
                    acc[i][j] += a[i] * bb[j];
        }
        __syncthreads();
    }
    #pragma unroll
    for (int i = 0; i < 4; ++i) {
        int o = o0 + ty * 4 + i;
        float bv = bout[o];
        #pragma unroll
        for (int j = 0; j < 4; ++j)
            hout[((size_t)b * D_ + o) * S_ + tx * 4 + j] = acc[i][j] + bv;
    }
}

// ---------------------------------------------------------------------------
// K5 (MFMA): y[b][d][l] = sum_s hout[b][d][s] * cm_bf[b][s][l]
// ---------------------------------------------------------------------------
__global__ __launch_bounds__(256) void k5_expand_mfma(
    const float* __restrict__ hout, const ushort_t* __restrict__ cm,
    float* __restrict__ y)
{
    __shared__ __align__(16) short A_lds[64][72];   // [d][s]
    __shared__ __align__(16) short B_lds[128][72];  // [l][s]
    const int l0 = blockIdx.x * 128;
    const int d0 = blockIdx.y * 64;
    const int b  = blockIdx.z;
    const int tid  = threadIdx.x;
    const int lane = tid & 63;
    const int wv   = tid >> 6;
    const int lm   = lane & 15, kg = lane >> 4;

    #pragma unroll
    for (int q = 0; q < 2; ++q) {
        int task = q * 256 + tid;
        int d = task >> 3, sg = (task & 7) * 8;
        *(short8*)&A_lds[d][sg] = ld_cvt8(hout + ((size_t)b * D_ + d0 + d) * S_ + sg);
    }
    #pragma unroll
    for (int q = 0; q < 4; ++q) {
        int l = tid & 127;
        int sg = (q * 2 + (tid >> 7)) * 8;
        const ushort_t* cp = cm + ((size_t)b * S_ + sg) * L_ + l0 + l;
        short8 s;
        #pragma unroll
        for (int r = 0; r < 8; ++r) s[r] = (short)cp[(size_t)r * L_];
        *(short8*)&B_lds[l][sg] = s;
    }
    __syncthreads();

    f32x4 acc[4][2];
    #pragma unroll
    for (int mi = 0; mi < 4; ++mi)
        #pragma unroll
        for (int nj = 0; nj < 2; ++nj)
            acc[mi][nj] = (f32x4){0.f, 0.f, 0.f, 0.f};
    #pragma unroll
    for (int ks = 0; ks < 2; ++ks) {
        short8 bb[2];
        #pragma unroll
        for (int nj = 0; nj < 2; ++nj)
            bb[nj] = *(const short8*)&B_lds[wv * 32 + nj * 16 + lm][ks * 32 + kg * 8];
        #pragma unroll
        for (int mi = 0; mi < 4; ++mi) {
            short8 a = *(const short8*)&A_lds[mi * 16 + lm][ks * 32 + kg * 8];
            #pragma unroll
            for (int nj = 0; nj < 2; ++nj)
                acc[mi][nj] = __builtin_amdgcn_mfma_f32_16x16x32_bf16(
                    a, bb[nj], acc[mi][nj], 0, 0, 0);
        }
    }
    const int col = l0 + wv * 32 + lm;
    #pragma unroll
    for (int mi = 0; mi < 4; ++mi)
        #pragma unroll
        for (int r = 0; r < 4; ++r)
            #pragma unroll
            for (int nj = 0; nj < 2; ++nj)
                y[((size_t)b * D_ + d0 + mi * 16 + kg * 4 + r) * L_ + col + nj * 16]
                    = acc[mi][nj][r];
}

// ---------------------------------------------------------------------------
extern "C" void kernel_launch(void* const* d_in, const int* in_sizes, int n_in,
                              void* d_out, int out_size, void* d_ws, size_t ws_size,
                              hipStream_t stream)
{
    const float* x      = (const float*)d_in[0];
    const float* w_bcdt = (const float*)d_in[3];
    const float* b_bcdt = (const float*)d_in[4];
    const float* w_dw   = (const float*)d_in[5];
    const float* b_dw   = (const float*)d_in[6];
    const float* w_hz   = (const float*)d_in[7];
    const float* b_hz   = (const float*)d_in[8];
    const float* w_out  = (const float*)d_in[9];
    const float* b_out  = (const float*)d_in[10];
    // d_in[11] = A_param: constant along softmax axis L -> cancels, unused
    const float* Dp     = (const float*)d_in[12];

    char* base = (char*)d_ws;
    ushort_t* pre_bf = (ushort_t*)(base);                    // 50.3 MB
    ushort_t* ab_bf  = (ushort_t*)(base + 50331648);         // 16.8 MB
    ushort_t* cm_bf  = (ushort_t*)(base + 67108864);         // 16.8 MB
    float*    hp     = (float*)   (base + 83886080);         // 8*2 MB = 16.8 MB
    float*    g      = (float*)   (base + 100663296);        //  2.1 MB

    float* y    = (float*)d_out;
    float* hout = (float*)d_out + YSZ;

    k1_bcdt_mfma  <<<dim3(32, 32),        256, 0, stream>>>(x, w_bcdt, b_bcdt, pre_bf);
    k2_conv       <<<dim3(128, 32),       256, 0, stream>>>(pre_bf, w_dw, b_dw, cm_bf, ab_bf);
    k3_hpart_mfma <<<dim3(2, 32, NCHUNK), 256, 0, stream>>>(x, ab_bf, hp);
    k4a_gate      <<<dim3(4, 32),         256, 0, stream>>>(hp, w_hz, b_hz, Dp, g);
    k4b_hout      <<<dim3(4, 32),         256, 0, stream>>>(g, w_out, b_out, hout);
    k5_expand_mfma<<<dim3(32, 4, 32),     256, 0, stream>>>(hout, cm_bf, y);
}